// Round 5
// baseline (2528.670 us; speedup 1.0000x reference)
//
#include <hip/hip_runtime.h>
#include <math.h>

#define Bsz 8
#define Nsz 2048
#define Ksz 8
#define NSLOPE 0.2f
#define EPSV 1e-5f
#define LOSCALE 2048.0f
#define INV_LOSCALE (1.0f / 2048.0f)

typedef _Float16 half8 __attribute__((ext_vector_type(8)));
typedef float floatx4 __attribute__((ext_vector_type(4)));

// K-chunk swizzle: within each aligned 32-half K-window of row r, the 8-half
// chunk at original position p is stored at position (p + (r>>1)) & 3.
__device__ __forceinline__ int swzk(int k, int row)
{
    return (k & ~31) | ((((k >> 3) + (row >> 1)) & 3) << 3) | (k & 7);
}

__device__ __forceinline__ void glds16(const _Float16* g, _Float16* l)
{
    __builtin_amdgcn_global_load_lds(
        (const __attribute__((address_space(1))) unsigned int*)g,
        (__attribute__((address_space(3))) unsigned int*)l, 16, 0, 0);
}

__device__ __forceinline__ void split2(float v, _Float16& h, _Float16& l)
{
    _Float16 hh = (_Float16)v;
    h = hh;
    l = (_Float16)((v - (float)hh) * LOSCALE);
}

__device__ __forceinline__ unsigned long long shfl_xor64(unsigned long long x, int off)
{
    unsigned lo = __shfl_xor((unsigned)x, off, 64);
    unsigned hi = __shfl_xor((unsigned)(x >> 32), off, 64);
    return ((unsigned long long)hi << 32) | lo;
}

// branchless descending insertion into sorted-8 (t[0] largest)
__device__ __forceinline__ void ins8(unsigned long long (&t)[8], unsigned long long key)
{
#pragma unroll
    for (int j = 7; j >= 1; --j)
        t[j] = (key > t[j - 1]) ? t[j - 1] : ((key > t[j]) ? key : t[j]);
    t[0] = (key > t[0]) ? key : t[0];
}

__device__ __forceinline__ unsigned long long mkkey(float v, int gn)
{
    unsigned u = __float_as_uint(v);
    u = (u & 0x80000000u) ? ~u : (u | 0x80000000u);
    return ((unsigned long long)u << 32) | (0xFFFFFFFFu - (unsigned)gn);
}

// ------------------------------------------------------------------
// fp16-split MFMA GEMM (weights/fc): C[b][m][n] = sum_k A[m][k]*Bt[n][k]
// Planes K-chunk-swizzled. Tile 128x128, BK=32, 4 waves x (64x64).
// ------------------------------------------------------------------
__launch_bounds__(256, 4) __global__
void hgemm_k(const _Float16* __restrict__ Ahi, const _Float16* __restrict__ Alo,
             long long sAb, int lda,
             const _Float16* __restrict__ Bhi, const _Float16* __restrict__ Blo,
             long long sBb, int ldb,
             float* __restrict__ C, long long sCb, int ldc,
             int Mreal, int Kk)
{
    __shared__ _Float16 sm[16384];   // Ahi[0,4096) Alo[4096) Bhi[8192) Blo[12288)
    const int b = blockIdx.z;
    const int m0 = blockIdx.y * 128, n0 = blockIdx.x * 128;
    const int tid = threadIdx.x;
    const int w = tid >> 6, lane = tid & 63;
    const int quad = lane >> 4, r16 = lane & 15;
    const int wm = (w >> 1) * 64, wn = (w & 1) * 64;
    const int sq = (r16 >> 1) & 3;

    const _Float16* Ah = Ahi + (long long)b * sAb;
    const _Float16* Al = Alo + (long long)b * sAb;
    const _Float16* Bh = Bhi + (long long)b * sBb;
    const _Float16* Bl = Blo + (long long)b * sBb;

    floatx4 acc_h[4][4], acc_m[4][4];
#pragma unroll
    for (int i = 0; i < 4; i++)
#pragma unroll
        for (int j = 0; j < 4; j++) {
            acc_h[i][j] = (floatx4){0.f, 0.f, 0.f, 0.f};
            acc_m[i][j] = (floatx4){0.f, 0.f, 0.f, 0.f};
        }

    const int kchunk = ((quad + sq) & 3) * 8;

    for (int k0 = 0; k0 < Kk; k0 += 32) {
#pragma unroll
        for (int q = 0; q < 2; q++) {
            int idx = q * 256 + tid;
            int row = idx >> 2;
            int seg = (idx & 3) * 8;
            long long aoff = (long long)(m0 + row) * lda + k0 + seg;
            long long boff = (long long)(n0 + row) * ldb + k0 + seg;
            glds16(Ah + aoff, &sm[idx * 8]);
            glds16(Al + aoff, &sm[4096 + idx * 8]);
            glds16(Bh + boff, &sm[8192 + idx * 8]);
            glds16(Bl + boff, &sm[12288 + idx * 8]);
        }
        __syncthreads();

        half8 ah[4], al[4];
#pragma unroll
        for (int i = 0; i < 4; i++) {
            int off = (wm + i * 16 + r16) * 32 + kchunk;
            ah[i] = *(const half8*)&sm[off];
            al[i] = *(const half8*)&sm[4096 + off];
        }
#pragma unroll
        for (int j = 0; j < 4; j++) {
            int off = (wn + j * 16 + r16) * 32 + kchunk;
            half8 bh = *(const half8*)&sm[8192 + off];
            half8 bl = *(const half8*)&sm[12288 + off];
#pragma unroll
            for (int i = 0; i < 4; i++) {
                acc_h[i][j] = __builtin_amdgcn_mfma_f32_16x16x32_f16(ah[i], bh, acc_h[i][j], 0, 0, 0);
                acc_m[i][j] = __builtin_amdgcn_mfma_f32_16x16x32_f16(ah[i], bl, acc_m[i][j], 0, 0, 0);
                acc_m[i][j] = __builtin_amdgcn_mfma_f32_16x16x32_f16(al[i], bh, acc_m[i][j], 0, 0, 0);
            }
        }
        __syncthreads();
    }

    float* Cb = C + (long long)b * sCb;
#pragma unroll
    for (int i = 0; i < 4; i++) {
#pragma unroll
        for (int r = 0; r < 4; r++) {
            int gm = m0 + wm + i * 16 + quad * 4 + r;
            if (gm >= Mreal) continue;
#pragma unroll
            for (int j = 0; j < 4; j++) {
                int gn = n0 + wn + j * 16 + r16;
                Cb[(long long)gm * ldc + gn] = acc_h[i][j][r] + acc_m[i][j][r] * INV_LOSCALE;
            }
        }
    }
}

// ------------------------------------------------------------------
// Pair GEMM + fused per-tile top-8: computes 128x128 tile of
// pair[b] = -(xx_m - 2*prevT.prev + xx_n), then per-row top-8 keys over
// this tile's 128 cols -> cand[b][row][tileX][8]. No pair write to HBM.
// ------------------------------------------------------------------
__launch_bounds__(256) __global__
void hgemm_cand_k(const _Float16* __restrict__ Phi, const _Float16* __restrict__ Plo,
                  long long sPb, int ldp,
                  unsigned long long* __restrict__ cand,
                  int Kk, const float* __restrict__ xx)
{
    __shared__ float smf[64 * 129];          // 33024 B; K-loop reuses as halfs
    _Float16* sm = (_Float16*)smf;
    const int b = blockIdx.z;
    const int m0 = blockIdx.y * 128, n0 = blockIdx.x * 128;
    const int tid = threadIdx.x;
    const int w = tid >> 6, lane = tid & 63;
    const int quad = lane >> 4, r16 = lane & 15;
    const int wm = (w >> 1) * 64, wn = (w & 1) * 64;
    const int sq = (r16 >> 1) & 3;

    const _Float16* Ah = Phi + (long long)b * sPb;
    const _Float16* Al = Plo + (long long)b * sPb;

    floatx4 acc_h[4][4], acc_m[4][4];
#pragma unroll
    for (int i = 0; i < 4; i++)
#pragma unroll
        for (int j = 0; j < 4; j++) {
            acc_h[i][j] = (floatx4){0.f, 0.f, 0.f, 0.f};
            acc_m[i][j] = (floatx4){0.f, 0.f, 0.f, 0.f};
        }

    const int kchunk = ((quad + sq) & 3) * 8;

    for (int k0 = 0; k0 < Kk; k0 += 32) {
#pragma unroll
        for (int q = 0; q < 2; q++) {
            int idx = q * 256 + tid;
            int row = idx >> 2;
            int seg = (idx & 3) * 8;
            long long aoff = (long long)(m0 + row) * ldp + k0 + seg;
            long long boff = (long long)(n0 + row) * ldp + k0 + seg;
            glds16(Ah + aoff, &sm[idx * 8]);
            glds16(Al + aoff, &sm[4096 + idx * 8]);
            glds16(Ah + boff, &sm[8192 + idx * 8]);
            glds16(Al + boff, &sm[12288 + idx * 8]);
        }
        __syncthreads();

        half8 ah[4], al[4];
#pragma unroll
        for (int i = 0; i < 4; i++) {
            int off = (wm + i * 16 + r16) * 32 + kchunk;
            ah[i] = *(const half8*)&sm[off];
            al[i] = *(const half8*)&sm[4096 + off];
        }
#pragma unroll
        for (int j = 0; j < 4; j++) {
            int off = (wn + j * 16 + r16) * 32 + kchunk;
            half8 bh = *(const half8*)&sm[8192 + off];
            half8 bl = *(const half8*)&sm[12288 + off];
#pragma unroll
            for (int i = 0; i < 4; i++) {
                acc_h[i][j] = __builtin_amdgcn_mfma_f32_16x16x32_f16(ah[i], bh, acc_h[i][j], 0, 0, 0);
                acc_m[i][j] = __builtin_amdgcn_mfma_f32_16x16x32_f16(ah[i], bl, acc_m[i][j], 0, 0, 0);
                acc_m[i][j] = __builtin_amdgcn_mfma_f32_16x16x32_f16(al[i], bh, acc_m[i][j], 0, 0, 0);
            }
        }
        __syncthreads();
    }

    const float* xxp = xx + (long long)b * Nsz;
    // two phases: rows [0,64) then [64,128) of the tile
#pragma unroll
    for (int p = 0; p < 2; p++) {
        __syncthreads();
        if ((w >> 1) == p) {
#pragma unroll
            for (int i = 0; i < 4; i++) {
#pragma unroll
                for (int r = 0; r < 4; r++) {
                    int row_l = i * 16 + quad * 4 + r;
                    float xm = xxp[m0 + p * 64 + row_l];
#pragma unroll
                    for (int j = 0; j < 4; j++) {
                        int col = wn + j * 16 + r16;
                        float a = acc_h[i][j][r] + acc_m[i][j][r] * INV_LOSCALE;
                        smf[row_l * 129 + col] = -((xm - 2.f * a) + xxp[n0 + col]);
                    }
                }
            }
        }
        __syncthreads();
        // scan: 4 threads per row, interleaved cols (bank-friendly)
        int row_l = tid >> 2, s = tid & 3;
        int gm = m0 + p * 64 + row_l;
        unsigned long long t[8] = {0, 0, 0, 0, 0, 0, 0, 0};
#pragma unroll
        for (int c = 0; c < 32; c++) {
            int col = s + c * 4;
            float v = smf[row_l * 129 + col];
            ins8(t, mkkey(v, n0 + col));
        }
        // merge the 4 threads of this row (lanes tid^1, tid^2 in same wave)
#pragma unroll
        for (int rnd = 1; rnd <= 2; rnd <<= 1) {
            unsigned long long oth[8];
#pragma unroll
            for (int j = 0; j < 8; j++) oth[j] = shfl_xor64(t[j], rnd);
#pragma unroll
            for (int j = 0; j < 8; j++) ins8(t, oth[j]);
        }
        if (s == 0) {
            unsigned long long* cp = cand +
                (((size_t)b * Nsz + gm) * 16 + blockIdx.x) * 8;
#pragma unroll
            for (int r = 0; r < 8; r++) cp[r] = t[r];
        }
    }
}

// merge 16 tiles x 8 candidates per row -> final top-8 indices
__global__ void merge_cand_k(const unsigned long long* __restrict__ cand,
                             int* __restrict__ idxo)
{
    int lane = threadIdx.x & 63;
    int row = blockIdx.x * 4 + (threadIdx.x >> 6);   // b*Nsz + n
    const unsigned long long* cr = cand + (size_t)row * 128;
    unsigned long long t[8] = {0, 0, 0, 0, 0, 0, 0, 0};
    ins8(t, cr[lane]);
    ins8(t, cr[lane + 64]);
    int* op = idxo + (size_t)row * 8;
#pragma unroll
    for (int r = 0; r < 8; r++) {
        unsigned long long best = t[0];
#pragma unroll
        for (int off = 32; off; off >>= 1) {
            unsigned long long o = shfl_xor64(best, off);
            if (o > best) best = o;
        }
        bool own = (t[0] == best);
#pragma unroll
        for (int j = 0; j < 7; j++) t[j] = own ? t[j + 1] : t[j];
        t[7] = own ? 0ull : t[7];
        if (lane == 0) op[r] = (int)(0xFFFFFFFFu - (unsigned)(best & 0xFFFFFFFFull));
    }
}

// ------------------------------------------------------------------
// fp32 SGEMM (layer-1 only, K=3)
// ------------------------------------------------------------------
__launch_bounds__(256) __global__
void sgemm_k(const float* __restrict__ A, int lda,
             const float* __restrict__ Bm, long long sBb, int ldb,
             float* __restrict__ C, long long sCb, int ldc,
             int M, int Kk)
{
    __shared__ float As[16][64];
    __shared__ float Bs[16][64];
    const int b = blockIdx.z;
    const float* Bb = Bm + (long long)b * sBb;
    const int m0 = blockIdx.y * 64, n0 = blockIdx.x * 64;
    const int tid = threadIdx.x;
    const int am = tid >> 2, ak = (tid & 3) * 4;
    const int bk = tid >> 6, bn = tid & 63;
    const int tx = tid & 15, ty = tid >> 4;
    float acc[4][4] = {};
    for (int k0 = 0; k0 < Kk; k0 += 16) {
#pragma unroll
        for (int i = 0; i < 4; i++) {
            int gk = k0 + ak + i;
            int gm = m0 + am;
            As[ak + i][am] = (gk < Kk && gm < M) ? A[(long long)gm * lda + gk] : 0.f;
        }
#pragma unroll
        for (int i = 0; i < 4; i++) {
            int kk = bk + i * 4;
            int gk = k0 + kk;
            Bs[kk][bn] = (gk < Kk) ? Bb[(long long)gk * ldb + (n0 + bn)] : 0.f;
        }
        __syncthreads();
#pragma unroll
        for (int kk = 0; kk < 16; kk++) {
            float a[4], bb2[4];
#pragma unroll
            for (int i = 0; i < 4; i++) a[i] = As[kk][ty * 4 + i];
#pragma unroll
            for (int j = 0; j < 4; j++) bb2[j] = Bs[kk][tx * 4 + j];
#pragma unroll
            for (int i = 0; i < 4; i++)
#pragma unroll
                for (int j = 0; j < 4; j++)
                    acc[i][j] = fmaf(a[i], bb2[j], acc[i][j]);
        }
        __syncthreads();
    }
    float* Cb = C + (long long)b * sCb;
#pragma unroll
    for (int i = 0; i < 4; i++) {
        int gm = m0 + ty * 4 + i;
        if (gm >= M) continue;
#pragma unroll
        for (int j = 0; j < 4; j++)
            Cb[(long long)gm * ldc + n0 + tx * 4 + j] = acc[i][j];
    }
}

// ------------------------------------------------------------------
// One-shot prep: xt transpose + layer-1 fp32 wcat + weight plane splits.
// ------------------------------------------------------------------
#define T0 16384
#define T1 (T0 + 192)
#define T2 (T1 + 16384)
#define T3 (T2 + 65536)
#define T4 (T3 + 262144)
#define T5 (T4 + 983040)
#define T6 (T5 + 524288)
#define T7 (T6 + 65536)
#define WOFF_E1 0
#define WOFF_E2 16384
#define WOFF_E3 81920
#define WOFF_W4 344064
#define WOFF_M1 1327104
#define WOFF_M2 1851392

__device__ __forceinline__ void split_plain(const float* W, _Float16* wh, _Float16* wl,
                                            size_t base, int t, int M, int Kk)
{
    int oo = t / Kk, c = t - oo * Kk;
    float v = (oo < M) ? W[(size_t)oo * Kk + c] : 0.f;
    _Float16 h, l;
    split2(v, h, l);
    size_t d = base + (size_t)oo * Kk + swzk(c, oo);
    wh[d] = h; wl[d] = l;
}

__device__ __forceinline__ void split_edge(const float* W, _Float16* wh, _Float16* wl,
                                           size_t base, int t, int O, int C)
{
    int oo = t / C, c = t - oo * C;
    float v;
    if (oo < O) v = W[(size_t)oo * 2 * C + c];
    else { int o2 = oo - O; v = W[(size_t)o2 * 2 * C + C + c] - W[(size_t)o2 * 2 * C + c]; }
    _Float16 h, l;
    split2(v, h, l);
    size_t d = base + (size_t)oo * C + swzk(c, oo);
    wh[d] = h; wl[d] = l;
}

__global__ void mega_prep_k(const float* __restrict__ x,
                            const float* __restrict__ W0, const float* __restrict__ W1,
                            const float* __restrict__ W2, const float* __restrict__ W3,
                            const float* __restrict__ W4, const float* __restrict__ Wm1,
                            const float* __restrict__ Wm2,
                            float* __restrict__ xt, float* __restrict__ wcat32,
                            _Float16* __restrict__ wh, _Float16* __restrict__ wl)
{
    int t = blockIdx.x * 256 + threadIdx.x;
    if (t < T0) {
        int n = t & (Nsz - 1), b = t >> 11;
#pragma unroll
        for (int c = 0; c < 3; c++)
            xt[((size_t)b * 3 + c) * Nsz + n] = x[((size_t)b * Nsz + n) * 3 + c];
    } else if (t < T1) {
        int u = t - T0;
        int oo = u / 3, c = u % 3;
        float a = W0[(size_t)oo * 6 + c];
        float b2 = W0[(size_t)oo * 6 + 3 + c];
        wcat32[(size_t)oo * 3 + c] = a;
        wcat32[(size_t)(64 + oo) * 3 + c] = b2 - a;
    } else if (t < T2) {
        split_edge(W1, wh, wl, WOFF_E1, t - T1, 128, 64);
    } else if (t < T3) {
        split_edge(W2, wh, wl, WOFF_E2, t - T2, 256, 128);
    } else if (t < T4) {
        split_edge(W3, wh, wl, WOFF_E3, t - T3, 512, 256);
    } else if (t < T5) {
        split_plain(W4, wh, wl, WOFF_W4, t - T4, 1024, 960);
    } else if (t < T6) {
        split_plain(Wm1, wh, wl, WOFF_M1, t - T5, 512, 1024);
    } else if (t < T7) {
        split_plain(Wm2, wh, wl, WOFF_M2, t - T6, 70, 512);
    }
}

// xx[b,n] = sum_c v^2 from planes, dropping lo^2 (matches GEMM's form).
__global__ void xx_planes_k(const _Float16* __restrict__ catA, const _Float16* __restrict__ catB,
                            float* __restrict__ xx, int off, int C)
{
    int t = blockIdx.x * 256 + threadIdx.x;
    if (t >= Bsz * Nsz) return;
    int n = t & (Nsz - 1), b = t >> 11;
    size_t base = ((size_t)b * Nsz + n) * 1024 + off;
    float s = 0.f;
    for (int c8 = 0; c8 < C / 8; c8++) {
        half8 h = *(const half8*)&catA[base + c8 * 8];
        half8 l = *(const half8*)&catB[base + c8 * 8];
#pragma unroll
        for (int e = 0; e < 8; e++) {
            float vh = (float)h[e];
            float vl = (float)l[e] * INV_LOSCALE;
            s = fmaf(vh, vh, s);
            s = fmaf(2.f * vh, vl, s);
        }
    }
    xx[t] = s;
}

// gather + max-pool + stats + transpose + split (swizzled write)
__global__ void gather_pool_t_k(const float* __restrict__ R, const int* __restrict__ idx,
                                _Float16* __restrict__ catA, _Float16* __restrict__ catB,
                                float* __restrict__ part, int O, int off)
{
    __shared__ float tile[64][65];
    const int tid = threadIdx.x;
    const int lane = tid & 63, w = tid >> 6;
    const int n0 = blockIdx.x * 64, o0 = blockIdx.y * 64, b = blockIdx.z;
    const int n = n0 + lane;

    int id[8];
    {
        const int* ip = idx + ((size_t)b * Nsz + n) * 8;
#pragma unroll
        for (int k = 0; k < 8; k++) id[k] = ip[k];
    }
    const float* Rb = R + (size_t)b * 2 * O * Nsz;
#pragma unroll
    for (int i = 0; i < 16; i++) {
        int o_l = w + i * 4;
        int o = o0 + o_l;
        const float* P = Rb + (size_t)o * Nsz;
        float q = Rb[(size_t)(O + o) * Nsz + n];
        float hmax = -INFINITY, s1 = 0.f, s2 = 0.f;
#pragma unroll
        for (int k = 0; k < 8; k++) {
            float h = P[id[k]] + q;
            hmax = fmaxf(hmax, h);
            s1 += h;
            s2 += h * h;
        }
        tile[o_l][lane] = hmax;
#pragma unroll
        for (int offs = 32; offs; offs >>= 1) {
            s1 += __shfl_xor(s1, offs, 64);
            s2 += __shfl_xor(s2, offs, 64);
        }
        if (lane == 0) {
            size_t pi = ((size_t)o * Bsz + b) * 32 + blockIdx.x;
            part[pi * 2] = s1;
            part[pi * 2 + 1] = s2;
        }
    }
    __syncthreads();
    int n_l = tid >> 2, quad = tid & 3;
    int nrow = n0 + n_l;
    half8 h0, h1, l0, l1;
#pragma unroll
    for (int e = 0; e < 8; e++) {
        _Float16 hh, ll;
        split2(tile[quad * 16 + e][n_l], hh, ll);
        h0[e] = hh; l0[e] = ll;
        split2(tile[quad * 16 + 8 + e][n_l], hh, ll);
        h1[e] = hh; l1[e] = ll;
    }
    size_t rowb = ((size_t)b * Nsz + nrow) * 1024;
    int c0 = off + o0 + quad * 16;
    *(half8*)&catA[rowb + swzk(c0, nrow)] = h0;
    *(half8*)&catA[rowb + swzk(c0 + 8, nrow)] = h1;
    *(half8*)&catB[rowb + swzk(c0, nrow)] = l0;
    *(half8*)&catB[rowb + swzk(c0 + 8, nrow)] = l1;
}

__global__ void stats_reduce_k(const float* __restrict__ part, float* __restrict__ stats)
{
    int o2 = blockIdx.x;
    int t = threadIdx.x;
    float s1 = part[((size_t)o2 * 256 + t) * 2];
    float s2 = part[((size_t)o2 * 256 + t) * 2 + 1];
#pragma unroll
    for (int off = 32; off; off >>= 1) { s1 += __shfl_xor(s1, off, 64); s2 += __shfl_xor(s2, off, 64); }
    __shared__ float sh[8];
    int w = t >> 6;
    if ((t & 63) == 0) { sh[w] = s1; sh[4 + w] = s2; }
    __syncthreads();
    if (t == 0) {
        stats[2 * o2] = sh[0] + sh[1] + sh[2] + sh[3];
        stats[2 * o2 + 1] = sh[4] + sh[5] + sh[6] + sh[7];
    }
}

__global__ void fc_stats_k(const float* __restrict__ buf, float* __restrict__ stats, int O)
{
    int oo = blockIdx.x;
    int t = threadIdx.x;
    float s1 = 0.f, s2 = 0.f;
    for (int i = t; i < Bsz * Nsz; i += 256) {
        int b = i >> 11, n = i & (Nsz - 1);
        float v = buf[((size_t)b * O + oo) * Nsz + n];
        s1 += v; s2 += v * v;
    }
#pragma unroll
    for (int off = 32; off; off >>= 1) { s1 += __shfl_xor(s1, off, 64); s2 += __shfl_xor(s2, off, 64); }
    __shared__ float sh[8];
    int w = t >> 6;
    if ((t & 63) == 0) { sh[w] = s1; sh[4 + w] = s2; }
    __syncthreads();
    if (t == 0) {
        stats[2 * oo] = sh[0] + sh[1] + sh[2] + sh[3];
        stats[2 * oo + 1] = sh[4] + sh[5] + sh[6] + sh[7];
    }
}

// in-place BN+lrelu on catT plane slice cols [off, off+O); swizzle-aware
__global__ void bn_t_k(_Float16* __restrict__ catA, _Float16* __restrict__ catB,
                       const float* __restrict__ stats, int off, int O, float invCnt)
{
    int per_n = O / 8;
    size_t t = (size_t)blockIdx.x * 256 + threadIdx.x;
    if (t >= (size_t)Bsz * Nsz * per_n) return;
    int c8 = (int)(t % per_n);
    size_t rest = t / per_n;
    int n = (int)(rest & (Nsz - 1));
    int b = (int)(rest >> 11);
    size_t base = ((size_t)b * Nsz + n) * 1024 + off + c8 * 8;
    int oo_base = ((c8 >> 2) << 5) + ((((c8 & 3) - (n >> 1)) & 3) << 3);
    half8 h = *(const half8*)&catA[base];
    half8 l = *(const half8*)&catB[base];
    half8 ho, lo;
#pragma unroll
    for (int e = 0; e < 8; e++) {
        int oo = oo_base + e;
        float mean = stats[2 * oo] * invCnt;
        float var = stats[2 * oo + 1] * invCnt - mean * mean;
        float v = (float)h[e] + (float)l[e] * INV_LOSCALE;
        float z = (v - mean) / sqrtf(var + EPSV);
        z = z >= 0.f ? z : NSLOPE * z;
        _Float16 hh, ll;
        split2(z, hh, ll);
        ho[e] = hh; lo[e] = ll;
    }
    *(half8*)&catA[base] = ho;
    *(half8*)&catB[base] = lo;
}

// fp32 [b][O][n] + BN + lrelu -> swizzled transposed planes
__global__ void bn_split_t_k(const float* __restrict__ src, const float* __restrict__ stats,
                             _Float16* __restrict__ dA, _Float16* __restrict__ dB,
                             int O, int ldt, float invCnt)
{
    __shared__ float tile[64][65];
    const int tid = threadIdx.x;
    const int n0 = blockIdx.x * 64, o0 = blockIdx.y * 64, b = blockIdx.z;
#pragma unroll
    for (int i = 0; i < 16; i++) {
        int flat = tid + 256 * i;
        int o_l = flat >> 6, n_l = flat & 63;
        int oo = o0 + o_l;
        float mean = stats[2 * oo] * invCnt;
        float var = stats[2 * oo + 1] * invCnt - mean * mean;
        float v = src[((size_t)b * O + oo) * Nsz + n0 + n_l];
        float z = (v - mean) / sqrtf(var + EPSV);
        tile[o_l][n_l] = z >= 0.f ? z : NSLOPE * z;
    }
    __syncthreads();
    int n_l = tid >> 2, quad = tid & 3;
    int nrow = n0 + n_l;
    half8 h0, h1, l0, l1;
#pragma unroll
    for (int e = 0; e < 8; e++) {
        _Float16 hh, ll;
        split2(tile[quad * 16 + e][n_l], hh, ll);
        h0[e] = hh; l0[e] = ll;
        split2(tile[quad * 16 + 8 + e][n_l], hh, ll);
        h1[e] = hh; l1[e] = ll;
    }
    size_t rowb = ((size_t)b * Nsz + nrow) * ldt;
    int c0 = o0 + quad * 16;
    *(half8*)&dA[rowb + swzk(c0, nrow)] = h0;
    *(half8*)&dA[rowb + swzk(c0 + 8, nrow)] = h1;
    *(half8*)&dB[rowb + swzk(c0, nrow)] = l0;
    *(half8*)&dB[rowb + swzk(c0 + 8, nrow)] = l1;
}

// argmax_n(logits + gumbel(u)); exact one-hot to out (70,B,N,1)
__global__ void gumbel_onehot_k(const float* __restrict__ logits, const float* __restrict__ u,
                                float* __restrict__ out)
{
    int lane = threadIdx.x & 63;
    int wv = threadIdx.x >> 6;
    int row = blockIdx.x * 4 + wv;      // row = b*70 + o
    int b = row / 70, oo = row % 70;
    const float* L = logits + (size_t)row * Nsz;
    const float* U = u + (size_t)row * Nsz;
    float bv = -INFINITY; int bi = 0x7fffffff;
    for (int n = lane; n < Nsz; n += 64) {
        float g = -logf(-logf(U[n]));
        float z = L[n] + g;
        if (z > bv) { bv = z; bi = n; }
    }
#pragma unroll
    for (int off = 32; off; off >>= 1) {
        float ov = __shfl_xor(bv, off, 64);
        int oi = __shfl_xor(bi, off, 64);
        if (ov > bv || (ov == bv && oi < bi)) { bv = ov; bi = oi; }
    }
    float* Or = out + ((size_t)oo * Bsz + b) * Nsz;
    for (int n = lane; n < Nsz; n += 64) Or[n] = (n == bi) ? 1.f : 0.f;
}

extern "C" void kernel_launch(void* const* d_in, const int* in_sizes, int n_in,
                              void* d_out, int out_size, void* d_ws, size_t ws_size,
                              hipStream_t stream)
{
    (void)in_sizes; (void)n_in; (void)out_size; (void)ws_size;
    const float* x   = (const float*)d_in[0];
    const int*   sn  = (const int*)d_in[1];
    const float* un  = (const float*)d_in[2];
    const float* W0  = (const float*)d_in[3];
    const float* W1  = (const float*)d_in[4];
    const float* W2  = (const float*)d_in[5];
    const float* W3  = (const float*)d_in[6];
    const float* W4  = (const float*)d_in[7];
    const float* Wm1 = (const float*)d_in[8];
    const float* Wm2 = (const float*)d_in[9];
    float* out = (float*)d_out;

    char* ws = (char*)d_ws;
    size_t o = 0;
    _Float16* catA = (_Float16*)(ws + o); o += (size_t)Bsz * Nsz * 1024 * 2;  // 33.5 MB
    _Float16* catB = (_Float16*)(ws + o); o += (size_t)Bsz * Nsz * 1024 * 2;  // 33.5 MB
    float* R       = (float*)(ws + o);    o += (size_t)Bsz * 1024 * Nsz * 4;  // 67 MB
    _Float16* wHi  = (_Float16*)(ws + o); o += (size_t)2 * 1024 * 1024 * 2;   // 4 MB
    _Float16* wLo  = (_Float16*)(ws + o); o += (size_t)2 * 1024 * 1024 * 2;   // 4 MB
    float* xt      = (float*)(ws + o);    o += (size_t)Bsz * 3 * Nsz * 4;
    float* xxb     = (float*)(ws + o);    o += (size_t)Bsz * Nsz * 4;
    float* wcat32  = (float*)(ws + o);    o += 4096;
    float* part    = (float*)(ws + o);    o += (size_t)512 * Bsz * 32 * 2 * 4;
    float* stats   = (float*)(ws + o);    o += 2048 * 4;
    int* idxb      = (int*)(ws + o);      o += (size_t)Bsz * Nsz * Ksz * 4;
    unsigned long long* cand = (unsigned long long*)R;  // 16.8 MB, dead before edge GEMM
    float* logits  = R + (size_t)12 * 1024 * 1024;      // inside R (hm region dead by then)

    const long long catStride = (long long)Nsz * 1024;

    // ---- one-shot prep ----
    mega_prep_k<<<(T7 + 255) / 256, 256, 0, stream>>>(x, W0, W1, W2, W3, W4, Wm1, Wm2,
                                                      xt, wcat32, wHi, wLo);

    // ---- edge layer 1 (C=3, O=64, idx = start_neighs), fp32 path ----
    sgemm_k<<<dim3(32, 2, Bsz), 256, 0, stream>>>(wcat32, 3, xt, 3LL * Nsz, Nsz,
                                                  R, 2LL * 64 * Nsz, Nsz, 128, 3);
    gather_pool_t_k<<<dim3(32, 1, Bsz), 256, 0, stream>>>(R, sn, catA, catB, part, 64, 0);
    stats_reduce_k<<<64, 256, 0, stream>>>(part, stats);
    bn_t_k<<<(int)(((size_t)Bsz * Nsz * 8 + 255) / 256), 256, 0, stream>>>(
        catA, catB, stats, 0, 64, 1.f / 131072.f);

    // ---- edge layers 2..4 ----
    struct LayerDesc { int C; int O; int prevOff; int catOff; size_t woff; };
    LayerDesc L[3] = {
        { 64, 128, 0, 64, WOFF_E1 },
        { 128, 256, 64, 192, WOFF_E2 },
        { 256, 512, 192, 448, WOFF_E3 },
    };
    for (int li = 0; li < 3; li++) {
        int C = L[li].C, O = L[li].O;
        int poff = L[li].prevOff;
        xx_planes_k<<<(Bsz * Nsz + 255) / 256, 256, 0, stream>>>(catA, catB, xxb, poff, C);
        // fused pair GEMM + per-tile top-8 candidates (all 8 batches)
        hgemm_cand_k<<<dim3(16, 16, Bsz), 256, 0, stream>>>(
            catA + poff, catB + poff, catStride, 1024, cand, C, xxb);
        merge_cand_k<<<Bsz * Nsz / 4, 256, 0, stream>>>(cand, idxb);
        // edge GEMM: R[b][2O][n] = wsplit @ prevT
        hgemm_k<<<dim3(16, 2 * O / 128, Bsz), 256, 0, stream>>>(
            wHi + L[li].woff, wLo + L[li].woff, 0, C, catA + poff, catB + poff, catStride, 1024,
            R, 2LL * O * Nsz, Nsz, 2 * O, C);
        gather_pool_t_k<<<dim3(32, O / 64, Bsz), 256, 0, stream>>>(
            R, idxb, catA, catB, part, O, L[li].catOff);
        stats_reduce_k<<<O, 256, 0, stream>>>(part, stats);
        bn_t_k<<<(int)(((size_t)Bsz * Nsz * (O / 8) + 255) / 256), 256, 0, stream>>>(
            catA, catB, stats, L[li].catOff, O, 1.f / 131072.f);
    }

    // ---- fc head ----
    hgemm_k<<<dim3(16, 8, Bsz), 256, 0, stream>>>(
        wHi + WOFF_W4, wLo + WOFF_W4, 0, 960, catA, catB, catStride, 1024,
        R, 1024LL * Nsz, Nsz, 1024, 960);
    fc_stats_k<<<1024, 256, 0, stream>>>(R, stats, 1024);
    bn_split_t_k<<<dim3(32, 16, Bsz), 256, 0, stream>>>(R, stats, catA, catB, 1024, 1024,
                                                        1.f / 16384.f);
    hgemm_k<<<dim3(16, 4, Bsz), 256, 0, stream>>>(
        wHi + WOFF_M1, wLo + WOFF_M1, 0, 1024, catA, catB, catStride, 1024,
        R, 512LL * Nsz, Nsz, 512, 1024);
    fc_stats_k<<<512, 256, 0, stream>>>(R, stats, 512);
    bn_split_t_k<<<dim3(32, 8, Bsz), 256, 0, stream>>>(R, stats, catA, catB, 512, 512,
                                                       1.f / 16384.f);
    hgemm_k<<<dim3(16, 1, Bsz), 256, 0, stream>>>(
        wHi + WOFF_M2, wLo + WOFF_M2, 0, 512, catA, catB, (long long)Nsz * 512, 512,
        logits, 70LL * Nsz, Nsz, 70, 512);

    gumbel_onehot_k<<<(Bsz * 70) / 4, 256, 0, stream>>>(logits, un, out);
}

// Round 6
// 1471.767 us; speedup vs baseline: 1.7181x; 1.7181x over previous
//
#include <hip/hip_runtime.h>
#include <math.h>

#define Bsz 8
#define Nsz 2048
#define Ksz 8
#define NSLOPE 0.2f
#define EPSV 1e-5f
#define LOSCALE 2048.0f
#define INV_LOSCALE (1.0f / 2048.0f)

typedef _Float16 half8 __attribute__((ext_vector_type(8)));
typedef float floatx4 __attribute__((ext_vector_type(4)));

// K-chunk swizzle: within each aligned 32-half K-window of row r, the 8-half
// chunk at original position p is stored at position (p + (r>>1)) & 3.
__device__ __forceinline__ int swzk(int k, int row)
{
    return (k & ~31) | ((((k >> 3) + (row >> 1)) & 3) << 3) | (k & 7);
}

__device__ __forceinline__ void glds16(const _Float16* g, _Float16* l)
{
    __builtin_amdgcn_global_load_lds(
        (const __attribute__((address_space(1))) unsigned int*)g,
        (__attribute__((address_space(3))) unsigned int*)l, 16, 0, 0);
}

__device__ __forceinline__ void split2(float v, _Float16& h, _Float16& l)
{
    _Float16 hh = (_Float16)v;
    h = hh;
    l = (_Float16)((v - (float)hh) * LOSCALE);
}

__device__ __forceinline__ unsigned long long shfl_xor64(unsigned long long x, int off)
{
    unsigned lo = __shfl_xor((unsigned)x, off, 64);
    unsigned hi = __shfl_xor((unsigned)(x >> 32), off, 64);
    return ((unsigned long long)hi << 32) | lo;
}

// branchless descending insertion into sorted-8 (t[0] largest)
__device__ __forceinline__ void ins8(unsigned long long (&t)[8], unsigned long long key)
{
#pragma unroll
    for (int j = 7; j >= 1; --j)
        t[j] = (key > t[j - 1]) ? t[j - 1] : ((key > t[j]) ? key : t[j]);
    t[0] = (key > t[0]) ? key : t[0];
}

__device__ __forceinline__ unsigned long long mkkey(float v, int gn)
{
    unsigned u = __float_as_uint(v);
    u = (u & 0x80000000u) ? ~u : (u | 0x80000000u);
    return ((unsigned long long)u << 32) | (0xFFFFFFFFu - (unsigned)gn);
}

// ------------------------------------------------------------------
// fp16-split MFMA GEMM (weights/fc): C[b][m][n] = sum_k A[m][k]*Bt[n][k]
// Planes K-chunk-swizzled. Tile 128x128, BK=32, 4 waves x (64x64).
// NOTE: no min-waves arg in launch_bounds — (256,4) forced VGPR=64 and
// spilled the 128-float accumulator to scratch (round-5: 3.4 GB HBM/dispatch).
// ------------------------------------------------------------------
__launch_bounds__(256) __global__
void hgemm_k(const _Float16* __restrict__ Ahi, const _Float16* __restrict__ Alo,
             long long sAb, int lda,
             const _Float16* __restrict__ Bhi, const _Float16* __restrict__ Blo,
             long long sBb, int ldb,
             float* __restrict__ C, long long sCb, int ldc,
             int Mreal, int Kk)
{
    __shared__ _Float16 sm[16384];   // Ahi[0,4096) Alo[4096) Bhi[8192) Blo[12288)
    const int b = blockIdx.z;
    const int m0 = blockIdx.y * 128, n0 = blockIdx.x * 128;
    const int tid = threadIdx.x;
    const int w = tid >> 6, lane = tid & 63;
    const int quad = lane >> 4, r16 = lane & 15;
    const int wm = (w >> 1) * 64, wn = (w & 1) * 64;
    const int sq = (r16 >> 1) & 3;

    const _Float16* Ah = Ahi + (long long)b * sAb;
    const _Float16* Al = Alo + (long long)b * sAb;
    const _Float16* Bh = Bhi + (long long)b * sBb;
    const _Float16* Bl = Blo + (long long)b * sBb;

    floatx4 acc_h[4][4], acc_m[4][4];
#pragma unroll
    for (int i = 0; i < 4; i++)
#pragma unroll
        for (int j = 0; j < 4; j++) {
            acc_h[i][j] = (floatx4){0.f, 0.f, 0.f, 0.f};
            acc_m[i][j] = (floatx4){0.f, 0.f, 0.f, 0.f};
        }

    const int kchunk = ((quad + sq) & 3) * 8;

    for (int k0 = 0; k0 < Kk; k0 += 32) {
#pragma unroll
        for (int q = 0; q < 2; q++) {
            int idx = q * 256 + tid;
            int row = idx >> 2;
            int seg = (idx & 3) * 8;
            long long aoff = (long long)(m0 + row) * lda + k0 + seg;
            long long boff = (long long)(n0 + row) * ldb + k0 + seg;
            glds16(Ah + aoff, &sm[idx * 8]);
            glds16(Al + aoff, &sm[4096 + idx * 8]);
            glds16(Bh + boff, &sm[8192 + idx * 8]);
            glds16(Bl + boff, &sm[12288 + idx * 8]);
        }
        __syncthreads();

        half8 ah[4], al[4];
#pragma unroll
        for (int i = 0; i < 4; i++) {
            int off = (wm + i * 16 + r16) * 32 + kchunk;
            ah[i] = *(const half8*)&sm[off];
            al[i] = *(const half8*)&sm[4096 + off];
        }
#pragma unroll
        for (int j = 0; j < 4; j++) {
            int off = (wn + j * 16 + r16) * 32 + kchunk;
            half8 bh = *(const half8*)&sm[8192 + off];
            half8 bl = *(const half8*)&sm[12288 + off];
#pragma unroll
            for (int i = 0; i < 4; i++) {
                acc_h[i][j] = __builtin_amdgcn_mfma_f32_16x16x32_f16(ah[i], bh, acc_h[i][j], 0, 0, 0);
                acc_m[i][j] = __builtin_amdgcn_mfma_f32_16x16x32_f16(ah[i], bl, acc_m[i][j], 0, 0, 0);
                acc_m[i][j] = __builtin_amdgcn_mfma_f32_16x16x32_f16(al[i], bh, acc_m[i][j], 0, 0, 0);
            }
        }
        __syncthreads();
    }

    float* Cb = C + (long long)b * sCb;
#pragma unroll
    for (int i = 0; i < 4; i++) {
#pragma unroll
        for (int r = 0; r < 4; r++) {
            int gm = m0 + wm + i * 16 + quad * 4 + r;
            if (gm >= Mreal) continue;
#pragma unroll
            for (int j = 0; j < 4; j++) {
                int gn = n0 + wn + j * 16 + r16;
                Cb[(long long)gm * ldc + gn] = acc_h[i][j][r] + acc_m[i][j][r] * INV_LOSCALE;
            }
        }
    }
}

// ------------------------------------------------------------------
// Pair GEMM + fused per-tile top-8: computes 128x128 tile of
// pair[b] = -(xx_m - 2*prevT.prev + xx_n), then per-row top-8 keys over
// this tile's 128 cols -> cand[b][row][tileX][8]. No pair write to HBM.
// ------------------------------------------------------------------
__launch_bounds__(256) __global__
void hgemm_cand_k(const _Float16* __restrict__ Phi, const _Float16* __restrict__ Plo,
                  long long sPb, int ldp,
                  unsigned long long* __restrict__ cand,
                  int Kk, const float* __restrict__ xx)
{
    __shared__ float smf[64 * 129];          // 33024 B; K-loop reuses as halfs
    _Float16* sm = (_Float16*)smf;
    const int b = blockIdx.z;
    const int m0 = blockIdx.y * 128, n0 = blockIdx.x * 128;
    const int tid = threadIdx.x;
    const int w = tid >> 6, lane = tid & 63;
    const int quad = lane >> 4, r16 = lane & 15;
    const int wm = (w >> 1) * 64, wn = (w & 1) * 64;
    const int sq = (r16 >> 1) & 3;

    const _Float16* Ah = Phi + (long long)b * sPb;
    const _Float16* Al = Plo + (long long)b * sPb;

    floatx4 acc_h[4][4], acc_m[4][4];
#pragma unroll
    for (int i = 0; i < 4; i++)
#pragma unroll
        for (int j = 0; j < 4; j++) {
            acc_h[i][j] = (floatx4){0.f, 0.f, 0.f, 0.f};
            acc_m[i][j] = (floatx4){0.f, 0.f, 0.f, 0.f};
        }

    const int kchunk = ((quad + sq) & 3) * 8;

    for (int k0 = 0; k0 < Kk; k0 += 32) {
#pragma unroll
        for (int q = 0; q < 2; q++) {
            int idx = q * 256 + tid;
            int row = idx >> 2;
            int seg = (idx & 3) * 8;
            long long aoff = (long long)(m0 + row) * ldp + k0 + seg;
            long long boff = (long long)(n0 + row) * ldp + k0 + seg;
            glds16(Ah + aoff, &sm[idx * 8]);
            glds16(Al + aoff, &sm[4096 + idx * 8]);
            glds16(Ah + boff, &sm[8192 + idx * 8]);
            glds16(Al + boff, &sm[12288 + idx * 8]);
        }
        __syncthreads();

        half8 ah[4], al[4];
#pragma unroll
        for (int i = 0; i < 4; i++) {
            int off = (wm + i * 16 + r16) * 32 + kchunk;
            ah[i] = *(const half8*)&sm[off];
            al[i] = *(const half8*)&sm[4096 + off];
        }
#pragma unroll
        for (int j = 0; j < 4; j++) {
            int off = (wn + j * 16 + r16) * 32 + kchunk;
            half8 bh = *(const half8*)&sm[8192 + off];
            half8 bl = *(const half8*)&sm[12288 + off];
#pragma unroll
            for (int i = 0; i < 4; i++) {
                acc_h[i][j] = __builtin_amdgcn_mfma_f32_16x16x32_f16(ah[i], bh, acc_h[i][j], 0, 0, 0);
                acc_m[i][j] = __builtin_amdgcn_mfma_f32_16x16x32_f16(ah[i], bl, acc_m[i][j], 0, 0, 0);
                acc_m[i][j] = __builtin_amdgcn_mfma_f32_16x16x32_f16(al[i], bh, acc_m[i][j], 0, 0, 0);
            }
        }
        __syncthreads();
    }

    const float* xxp = xx + (long long)b * Nsz;
    // two phases: rows [0,64) then [64,128) of the tile
#pragma unroll
    for (int p = 0; p < 2; p++) {
        __syncthreads();
        if ((w >> 1) == p) {
#pragma unroll
            for (int i = 0; i < 4; i++) {
#pragma unroll
                for (int r = 0; r < 4; r++) {
                    int row_l = i * 16 + quad * 4 + r;
                    float xm = xxp[m0 + p * 64 + row_l];
#pragma unroll
                    for (int j = 0; j < 4; j++) {
                        int col = wn + j * 16 + r16;
                        float a = acc_h[i][j][r] + acc_m[i][j][r] * INV_LOSCALE;
                        smf[row_l * 129 + col] = -((xm - 2.f * a) + xxp[n0 + col]);
                    }
                }
            }
        }
        __syncthreads();
        // scan: 4 threads per row, interleaved cols
        int row_l = tid >> 2, s = tid & 3;
        int gm = m0 + p * 64 + row_l;
        unsigned long long t[8] = {0, 0, 0, 0, 0, 0, 0, 0};
#pragma unroll
        for (int c = 0; c < 32; c++) {
            int col = s + c * 4;
            float v = smf[row_l * 129 + col];
            ins8(t, mkkey(v, n0 + col));
        }
        // merge the 4 threads of this row
#pragma unroll
        for (int rnd = 1; rnd <= 2; rnd <<= 1) {
            unsigned long long oth[8];
#pragma unroll
            for (int j = 0; j < 8; j++) oth[j] = shfl_xor64(t[j], rnd);
#pragma unroll
            for (int j = 0; j < 8; j++) ins8(t, oth[j]);
        }
        if (s == 0) {
            unsigned long long* cp = cand +
                (((size_t)b * Nsz + gm) * 16 + blockIdx.x) * 8;
#pragma unroll
            for (int r = 0; r < 8; r++) cp[r] = t[r];
        }
    }
}

// merge 16 tiles x 8 candidates per row -> final top-8 indices
__global__ void merge_cand_k(const unsigned long long* __restrict__ cand,
                             int* __restrict__ idxo)
{
    int lane = threadIdx.x & 63;
    int row = blockIdx.x * 4 + (threadIdx.x >> 6);   // b*Nsz + n
    const unsigned long long* cr = cand + (size_t)row * 128;
    unsigned long long t[8] = {0, 0, 0, 0, 0, 0, 0, 0};
    ins8(t, cr[lane]);
    ins8(t, cr[lane + 64]);
    int* op = idxo + (size_t)row * 8;
#pragma unroll
    for (int r = 0; r < 8; r++) {
        unsigned long long best = t[0];
#pragma unroll
        for (int off = 32; off; off >>= 1) {
            unsigned long long o = shfl_xor64(best, off);
            if (o > best) best = o;
        }
        bool own = (t[0] == best);
#pragma unroll
        for (int j = 0; j < 7; j++) t[j] = own ? t[j + 1] : t[j];
        t[7] = own ? 0ull : t[7];
        if (lane == 0) op[r] = (int)(0xFFFFFFFFu - (unsigned)(best & 0xFFFFFFFFull));
    }
}

// ------------------------------------------------------------------
// fp32 SGEMM (layer-1 only, K=3)
// ------------------------------------------------------------------
__launch_bounds__(256) __global__
void sgemm_k(const float* __restrict__ A, int lda,
             const float* __restrict__ Bm, long long sBb, int ldb,
             float* __restrict__ C, long long sCb, int ldc,
             int M, int Kk)
{
    __shared__ float As[16][64];
    __shared__ float Bs[16][64];
    const int b = blockIdx.z;
    const float* Bb = Bm + (long long)b * sBb;
    const int m0 = blockIdx.y * 64, n0 = blockIdx.x * 64;
    const int tid = threadIdx.x;
    const int am = tid >> 2, ak = (tid & 3) * 4;
    const int bk = tid >> 6, bn = tid & 63;
    const int tx = tid & 15, ty = tid >> 4;
    float acc[4][4] = {};
    for (int k0 = 0; k0 < Kk; k0 += 16) {
#pragma unroll
        for (int i = 0; i < 4; i++) {
            int gk = k0 + ak + i;
            int gm = m0 + am;
            As[ak + i][am] = (gk < Kk && gm < M) ? A[(long long)gm * lda + gk] : 0.f;
        }
#pragma unroll
        for (int i = 0; i < 4; i++) {
            int kk = bk + i * 4;
            int gk = k0 + kk;
            Bs[kk][bn] = (gk < Kk) ? Bb[(long long)gk * ldb + (n0 + bn)] : 0.f;
        }
        __syncthreads();
#pragma unroll
        for (int kk = 0; kk < 16; kk++) {
            float a[4], bb2[4];
#pragma unroll
            for (int i = 0; i < 4; i++) a[i] = As[kk][ty * 4 + i];
#pragma unroll
            for (int j = 0; j < 4; j++) bb2[j] = Bs[kk][tx * 4 + j];
#pragma unroll
            for (int i = 0; i < 4; i++)
#pragma unroll
                for (int j = 0; j < 4; j++)
                    acc[i][j] = fmaf(a[i], bb2[j], acc[i][j]);
        }
        __syncthreads();
    }
    float* Cb = C + (long long)b * sCb;
#pragma unroll
    for (int i = 0; i < 4; i++) {
        int gm = m0 + ty * 4 + i;
        if (gm >= M) continue;
#pragma unroll
        for (int j = 0; j < 4; j++)
            Cb[(long long)gm * ldc + n0 + tx * 4 + j] = acc[i][j];
    }
}

// ------------------------------------------------------------------
// One-shot prep: xt transpose + layer-1 fp32 wcat + weight plane splits.
// ------------------------------------------------------------------
#define T0 16384
#define T1 (T0 + 192)
#define T2 (T1 + 16384)
#define T3 (T2 + 65536)
#define T4 (T3 + 262144)
#define T5 (T4 + 983040)
#define T6 (T5 + 524288)
#define T7 (T6 + 65536)
#define WOFF_E1 0
#define WOFF_E2 16384
#define WOFF_E3 81920
#define WOFF_W4 344064
#define WOFF_M1 1327104
#define WOFF_M2 1851392

__device__ __forceinline__ void split_plain(const float* W, _Float16* wh, _Float16* wl,
                                            size_t base, int t, int M, int Kk)
{
    int oo = t / Kk, c = t - oo * Kk;
    float v = (oo < M) ? W[(size_t)oo * Kk + c] : 0.f;
    _Float16 h, l;
    split2(v, h, l);
    size_t d = base + (size_t)oo * Kk + swzk(c, oo);
    wh[d] = h; wl[d] = l;
}

__device__ __forceinline__ void split_edge(const float* W, _Float16* wh, _Float16* wl,
                                           size_t base, int t, int O, int C)
{
    int oo = t / C, c = t - oo * C;
    float v;
    if (oo < O) v = W[(size_t)oo * 2 * C + c];
    else { int o2 = oo - O; v = W[(size_t)o2 * 2 * C + C + c] - W[(size_t)o2 * 2 * C + c]; }
    _Float16 h, l;
    split2(v, h, l);
    size_t d = base + (size_t)oo * C + swzk(c, oo);
    wh[d] = h; wl[d] = l;
}

__global__ void mega_prep_k(const float* __restrict__ x,
                            const float* __restrict__ W0, const float* __restrict__ W1,
                            const float* __restrict__ W2, const float* __restrict__ W3,
                            const float* __restrict__ W4, const float* __restrict__ Wm1,
                            const float* __restrict__ Wm2,
                            float* __restrict__ xt, float* __restrict__ wcat32,
                            _Float16* __restrict__ wh, _Float16* __restrict__ wl)
{
    int t = blockIdx.x * 256 + threadIdx.x;
    if (t < T0) {
        int n = t & (Nsz - 1), b = t >> 11;
#pragma unroll
        for (int c = 0; c < 3; c++)
            xt[((size_t)b * 3 + c) * Nsz + n] = x[((size_t)b * Nsz + n) * 3 + c];
    } else if (t < T1) {
        int u = t - T0;
        int oo = u / 3, c = u % 3;
        float a = W0[(size_t)oo * 6 + c];
        float b2 = W0[(size_t)oo * 6 + 3 + c];
        wcat32[(size_t)oo * 3 + c] = a;
        wcat32[(size_t)(64 + oo) * 3 + c] = b2 - a;
    } else if (t < T2) {
        split_edge(W1, wh, wl, WOFF_E1, t - T1, 128, 64);
    } else if (t < T3) {
        split_edge(W2, wh, wl, WOFF_E2, t - T2, 256, 128);
    } else if (t < T4) {
        split_edge(W3, wh, wl, WOFF_E3, t - T3, 512, 256);
    } else if (t < T5) {
        split_plain(W4, wh, wl, WOFF_W4, t - T4, 1024, 960);
    } else if (t < T6) {
        split_plain(Wm1, wh, wl, WOFF_M1, t - T5, 512, 1024);
    } else if (t < T7) {
        split_plain(Wm2, wh, wl, WOFF_M2, t - T6, 70, 512);
    }
}

// xx[b,n] = sum_c v^2 from planes, dropping lo^2 (matches GEMM's form).
__global__ void xx_planes_k(const _Float16* __restrict__ catA, const _Float16* __restrict__ catB,
                            float* __restrict__ xx, int off, int C)
{
    int t = blockIdx.x * 256 + threadIdx.x;
    if (t >= Bsz * Nsz) return;
    int n = t & (Nsz - 1), b = t >> 11;
    size_t base = ((size_t)b * Nsz + n) * 1024 + off;
    float s = 0.f;
    for (int c8 = 0; c8 < C / 8; c8++) {
        half8 h = *(const half8*)&catA[base + c8 * 8];
        half8 l = *(const half8*)&catB[base + c8 * 8];
#pragma unroll
        for (int e = 0; e < 8; e++) {
            float vh = (float)h[e];
            float vl = (float)l[e] * INV_LOSCALE;
            s = fmaf(vh, vh, s);
            s = fmaf(2.f * vh, vl, s);
        }
    }
    xx[t] = s;
}

// gather + max-pool + stats + transpose + split (swizzled write)
__global__ void gather_pool_t_k(const float* __restrict__ R, const int* __restrict__ idx,
                                _Float16* __restrict__ catA, _Float16* __restrict__ catB,
                                float* __restrict__ part, int O, int off)
{
    __shared__ float tile[64][65];
    const int tid = threadIdx.x;
    const int lane = tid & 63, w = tid >> 6;
    const int n0 = blockIdx.x * 64, o0 = blockIdx.y * 64, b = blockIdx.z;
    const int n = n0 + lane;

    int id[8];
    {
        const int* ip = idx + ((size_t)b * Nsz + n) * 8;
#pragma unroll
        for (int k = 0; k < 8; k++) id[k] = ip[k];
    }
    const float* Rb = R + (size_t)b * 2 * O * Nsz;
#pragma unroll
    for (int i = 0; i < 16; i++) {
        int o_l = w + i * 4;
        int o = o0 + o_l;
        const float* P = Rb + (size_t)o * Nsz;
        float q = Rb[(size_t)(O + o) * Nsz + n];
        float hmax = -INFINITY, s1 = 0.f, s2 = 0.f;
#pragma unroll
        for (int k = 0; k < 8; k++) {
            float h = P[id[k]] + q;
            hmax = fmaxf(hmax, h);
            s1 += h;
            s2 += h * h;
        }
        tile[o_l][lane] = hmax;
#pragma unroll
        for (int offs = 32; offs; offs >>= 1) {
            s1 += __shfl_xor(s1, offs, 64);
            s2 += __shfl_xor(s2, offs, 64);
        }
        if (lane == 0) {
            size_t pi = ((size_t)o * Bsz + b) * 32 + blockIdx.x;
            part[pi * 2] = s1;
            part[pi * 2 + 1] = s2;
        }
    }
    __syncthreads();
    int n_l = tid >> 2, quad = tid & 3;
    int nrow = n0 + n_l;
    half8 h0, h1, l0, l1;
#pragma unroll
    for (int e = 0; e < 8; e++) {
        _Float16 hh, ll;
        split2(tile[quad * 16 + e][n_l], hh, ll);
        h0[e] = hh; l0[e] = ll;
        split2(tile[quad * 16 + 8 + e][n_l], hh, ll);
        h1[e] = hh; l1[e] = ll;
    }
    size_t rowb = ((size_t)b * Nsz + nrow) * 1024;
    int c0 = off + o0 + quad * 16;
    *(half8*)&catA[rowb + swzk(c0, nrow)] = h0;
    *(half8*)&catA[rowb + swzk(c0 + 8, nrow)] = h1;
    *(half8*)&catB[rowb + swzk(c0, nrow)] = l0;
    *(half8*)&catB[rowb + swzk(c0 + 8, nrow)] = l1;
}

__global__ void stats_reduce_k(const float* __restrict__ part, float* __restrict__ stats)
{
    int o2 = blockIdx.x;
    int t = threadIdx.x;
    float s1 = part[((size_t)o2 * 256 + t) * 2];
    float s2 = part[((size_t)o2 * 256 + t) * 2 + 1];
#pragma unroll
    for (int off = 32; off; off >>= 1) { s1 += __shfl_xor(s1, off, 64); s2 += __shfl_xor(s2, off, 64); }
    __shared__ float sh[8];
    int w = t >> 6;
    if ((t & 63) == 0) { sh[w] = s1; sh[4 + w] = s2; }
    __syncthreads();
    if (t == 0) {
        stats[2 * o2] = sh[0] + sh[1] + sh[2] + sh[3];
        stats[2 * o2 + 1] = sh[4] + sh[5] + sh[6] + sh[7];
    }
}

__global__ void fc_stats_k(const float* __restrict__ buf, float* __restrict__ stats, int O)
{
    int oo = blockIdx.x;
    int t = threadIdx.x;
    float s1 = 0.f, s2 = 0.f;
    for (int i = t; i < Bsz * Nsz; i += 256) {
        int b = i >> 11, n = i & (Nsz - 1);
        float v = buf[((size_t)b * O + oo) * Nsz + n];
        s1 += v; s2 += v * v;
    }
#pragma unroll
    for (int off = 32; off; off >>= 1) { s1 += __shfl_xor(s1, off, 64); s2 += __shfl_xor(s2, off, 64); }
    __shared__ float sh[8];
    int w = t >> 6;
    if ((t & 63) == 0) { sh[w] = s1; sh[4 + w] = s2; }
    __syncthreads();
    if (t == 0) {
        stats[2 * oo] = sh[0] + sh[1] + sh[2] + sh[3];
        stats[2 * oo + 1] = sh[4] + sh[5] + sh[6] + sh[7];
    }
}

// in-place BN+lrelu on catT plane slice cols [off, off+O); swizzle-aware
__global__ void bn_t_k(_Float16* __restrict__ catA, _Float16* __restrict__ catB,
                       const float* __restrict__ stats, int off, int O, float invCnt)
{
    int per_n = O / 8;
    size_t t = (size_t)blockIdx.x * 256 + threadIdx.x;
    if (t >= (size_t)Bsz * Nsz * per_n) return;
    int c8 = (int)(t % per_n);
    size_t rest = t / per_n;
    int n = (int)(rest & (Nsz - 1));
    int b = (int)(rest >> 11);
    size_t base = ((size_t)b * Nsz + n) * 1024 + off + c8 * 8;
    int oo_base = ((c8 >> 2) << 5) + ((((c8 & 3) - (n >> 1)) & 3) << 3);
    half8 h = *(const half8*)&catA[base];
    half8 l = *(const half8*)&catB[base];
    half8 ho, lo;
#pragma unroll
    for (int e = 0; e < 8; e++) {
        int oo = oo_base + e;
        float mean = stats[2 * oo] * invCnt;
        float var = stats[2 * oo + 1] * invCnt - mean * mean;
        float v = (float)h[e] + (float)l[e] * INV_LOSCALE;
        float z = (v - mean) / sqrtf(var + EPSV);
        z = z >= 0.f ? z : NSLOPE * z;
        _Float16 hh, ll;
        split2(z, hh, ll);
        ho[e] = hh; lo[e] = ll;
    }
    *(half8*)&catA[base] = ho;
    *(half8*)&catB[base] = lo;
}

// fp32 [b][O][n] + BN + lrelu -> swizzled transposed planes
__global__ void bn_split_t_k(const float* __restrict__ src, const float* __restrict__ stats,
                             _Float16* __restrict__ dA, _Float16* __restrict__ dB,
                             int O, int ldt, float invCnt)
{
    __shared__ float tile[64][65];
    const int tid = threadIdx.x;
    const int n0 = blockIdx.x * 64, o0 = blockIdx.y * 64, b = blockIdx.z;
#pragma unroll
    for (int i = 0; i < 16; i++) {
        int flat = tid + 256 * i;
        int o_l = flat >> 6, n_l = flat & 63;
        int oo = o0 + o_l;
        float mean = stats[2 * oo] * invCnt;
        float var = stats[2 * oo + 1] * invCnt - mean * mean;
        float v = src[((size_t)b * O + oo) * Nsz + n0 + n_l];
        float z = (v - mean) / sqrtf(var + EPSV);
        tile[o_l][n_l] = z >= 0.f ? z : NSLOPE * z;
    }
    __syncthreads();
    int n_l = tid >> 2, quad = tid & 3;
    int nrow = n0 + n_l;
    half8 h0, h1, l0, l1;
#pragma unroll
    for (int e = 0; e < 8; e++) {
        _Float16 hh, ll;
        split2(tile[quad * 16 + e][n_l], hh, ll);
        h0[e] = hh; l0[e] = ll;
        split2(tile[quad * 16 + 8 + e][n_l], hh, ll);
        h1[e] = hh; l1[e] = ll;
    }
    size_t rowb = ((size_t)b * Nsz + nrow) * ldt;
    int c0 = o0 + quad * 16;
    *(half8*)&dA[rowb + swzk(c0, nrow)] = h0;
    *(half8*)&dA[rowb + swzk(c0 + 8, nrow)] = h1;
    *(half8*)&dB[rowb + swzk(c0, nrow)] = l0;
    *(half8*)&dB[rowb + swzk(c0 + 8, nrow)] = l1;
}

// argmax_n(logits + gumbel(u)); exact one-hot to out (70,B,N,1)
__global__ void gumbel_onehot_k(const float* __restrict__ logits, const float* __restrict__ u,
                                float* __restrict__ out)
{
    int lane = threadIdx.x & 63;
    int wv = threadIdx.x >> 6;
    int row = blockIdx.x * 4 + wv;      // row = b*70 + o
    int b = row / 70, oo = row % 70;
    const float* L = logits + (size_t)row * Nsz;
    const float* U = u + (size_t)row * Nsz;
    float bv = -INFINITY; int bi = 0x7fffffff;
    for (int n = lane; n < Nsz; n += 64) {
        float g = -logf(-logf(U[n]));
        float z = L[n] + g;
        if (z > bv) { bv = z; bi = n; }
    }
#pragma unroll
    for (int off = 32; off; off >>= 1) {
        float ov = __shfl_xor(bv, off, 64);
        int oi = __shfl_xor(bi, off, 64);
        if (ov > bv || (ov == bv && oi < bi)) { bv = ov; bi = oi; }
    }
    float* Or = out + ((size_t)oo * Bsz + b) * Nsz;
    for (int n = lane; n < Nsz; n += 64) Or[n] = (n == bi) ? 1.f : 0.f;
}

extern "C" void kernel_launch(void* const* d_in, const int* in_sizes, int n_in,
                              void* d_out, int out_size, void* d_ws, size_t ws_size,
                              hipStream_t stream)
{
    (void)in_sizes; (void)n_in; (void)out_size; (void)ws_size;
    const float* x   = (const float*)d_in[0];
    const int*   sn  = (const int*)d_in[1];
    const float* un  = (const float*)d_in[2];
    const float* W0  = (const float*)d_in[3];
    const float* W1  = (const float*)d_in[4];
    const float* W2  = (const float*)d_in[5];
    const float* W3  = (const float*)d_in[6];
    const float* W4  = (const float*)d_in[7];
    const float* Wm1 = (const float*)d_in[8];
    const float* Wm2 = (const float*)d_in[9];
    float* out = (float*)d_out;

    char* ws = (char*)d_ws;
    size_t o = 0;
    _Float16* catA = (_Float16*)(ws + o); o += (size_t)Bsz * Nsz * 1024 * 2;  // 33.5 MB
    _Float16* catB = (_Float16*)(ws + o); o += (size_t)Bsz * Nsz * 1024 * 2;  // 33.5 MB
    float* R       = (float*)(ws + o);    o += (size_t)Bsz * 1024 * Nsz * 4;  // 67 MB
    _Float16* wHi  = (_Float16*)(ws + o); o += (size_t)2 * 1024 * 1024 * 2;   // 4 MB
    _Float16* wLo  = (_Float16*)(ws + o); o += (size_t)2 * 1024 * 1024 * 2;   // 4 MB
    float* xt      = (float*)(ws + o);    o += (size_t)Bsz * 3 * Nsz * 4;
    float* xxb     = (float*)(ws + o);    o += (size_t)Bsz * Nsz * 4;
    float* wcat32  = (float*)(ws + o);    o += 4096;
    float* part    = (float*)(ws + o);    o += (size_t)512 * Bsz * 32 * 2 * 4;
    float* stats   = (float*)(ws + o);    o += 2048 * 4;
    int* idxb      = (int*)(ws + o);      o += (size_t)Bsz * Nsz * Ksz * 4;
    unsigned long long* cand = (unsigned long long*)R;  // 16.8 MB, dead before edge GEMM
    float* logits  = R + (size_t)12 * 1024 * 1024;      // inside R (hm region dead by then)

    const long long catStride = (long long)Nsz * 1024;

    // ---- one-shot prep ----
    mega_prep_k<<<(T7 + 255) / 256, 256, 0, stream>>>(x, W0, W1, W2, W3, W4, Wm1, Wm2,
                                                      xt, wcat32, wHi, wLo);

    // ---- edge layer 1 (C=3, O=64, idx = start_neighs), fp32 path ----
    sgemm_k<<<dim3(32, 2, Bsz), 256, 0, stream>>>(wcat32, 3, xt, 3LL * Nsz, Nsz,
                                                  R, 2LL * 64 * Nsz, Nsz, 128, 3);
    gather_pool_t_k<<<dim3(32, 1, Bsz), 256, 0, stream>>>(R, sn, catA, catB, part, 64, 0);
    stats_reduce_k<<<64, 256, 0, stream>>>(part, stats);
    bn_t_k<<<(int)(((size_t)Bsz * Nsz * 8 + 255) / 256), 256, 0, stream>>>(
        catA, catB, stats, 0, 64, 1.f / 131072.f);

    // ---- edge layers 2..4 ----
    struct LayerDesc { int C; int O; int prevOff; int catOff; size_t woff; };
    LayerDesc L[3] = {
        { 64, 128, 0, 64, WOFF_E1 },
        { 128, 256, 64, 192, WOFF_E2 },
        { 256, 512, 192, 448, WOFF_E3 },
    };
    for (int li = 0; li < 3; li++) {
        int C = L[li].C, O = L[li].O;
        int poff = L[li].prevOff;
        xx_planes_k<<<(Bsz * Nsz + 255) / 256, 256, 0, stream>>>(catA, catB, xxb, poff, C);
        hgemm_cand_k<<<dim3(16, 16, Bsz), 256, 0, stream>>>(
            catA + poff, catB + poff, catStride, 1024, cand, C, xxb);
        merge_cand_k<<<Bsz * Nsz / 4, 256, 0, stream>>>(cand, idxb);
        hgemm_k<<<dim3(16, 2 * O / 128, Bsz), 256, 0, stream>>>(
            wHi + L[li].woff, wLo + L[li].woff, 0, C, catA + poff, catB + poff, catStride, 1024,
            R, 2LL * O * Nsz, Nsz, 2 * O, C);
        gather_pool_t_k<<<dim3(32, O / 64, Bsz), 256, 0, stream>>>(
            R, idxb, catA, catB, part, O, L[li].catOff);
        stats_reduce_k<<<O, 256, 0, stream>>>(part, stats);
        bn_t_k<<<(int)(((size_t)Bsz * Nsz * (O / 8) + 255) / 256), 256, 0, stream>>>(
            catA, catB, stats, L[li].catOff, O, 1.f / 131072.f);
    }

    // ---- fc head ----
    hgemm_k<<<dim3(16, 8, Bsz), 256, 0, stream>>>(
        wHi + WOFF_W4, wLo + WOFF_W4, 0, 960, catA, catB, catStride, 1024,
        R, 1024LL * Nsz, Nsz, 1024, 960);
    fc_stats_k<<<1024, 256, 0, stream>>>(R, stats, 1024);
    bn_split_t_k<<<dim3(32, 16, Bsz), 256, 0, stream>>>(R, stats, catA, catB, 1024, 1024,
                                                        1.f / 16384.f);
    hgemm_k<<<dim3(16, 4, Bsz), 256, 0, stream>>>(
        wHi + WOFF_M1, wLo + WOFF_M1, 0, 1024, catA, catB, catStride, 1024,
        R, 512LL * Nsz, Nsz, 512, 1024);
    fc_stats_k<<<512, 256, 0, stream>>>(R, stats, 512);
    bn_split_t_k<<<dim3(32, 8, Bsz), 256, 0, stream>>>(R, stats, catA, catB, 512, 512,
                                                       1.f / 16384.f);
    hgemm_k<<<dim3(16, 1, Bsz), 256, 0, stream>>>(
        wHi + WOFF_M2, wLo + WOFF_M2, 0, 512, catA, catB, (long long)Nsz * 512, 512,
        logits, 70LL * Nsz, Nsz, 70, 512);

    gumbel_onehot_k<<<(Bsz * 70) / 4, 256, 0, stream>>>(logits, un, out);
}

// Round 7
// 1191.371 us; speedup vs baseline: 2.1225x; 1.2354x over previous
//
#include <hip/hip_runtime.h>
#include <math.h>

#define Bsz 8
#define Nsz 2048
#define Ksz 8
#define NSLOPE 0.2f
#define EPSV 1e-5f
#define LOSCALE 2048.0f
#define INV_LOSCALE (1.0f / 2048.0f)

typedef _Float16 half8 __attribute__((ext_vector_type(8)));
typedef float floatx4 __attribute__((ext_vector_type(4)));

// K-chunk swizzle: within each aligned 32-half K-window of row r, the 8-half
// chunk at original position p is stored at position (p + (r>>1)) & 3.
__device__ __forceinline__ int swzk(int k, int row)
{
    return (k & ~31) | ((((k >> 3) + (row >> 1)) & 3) << 3) | (k & 7);
}

__device__ __forceinline__ void glds16(const _Float16* g, _Float16* l)
{
    __builtin_amdgcn_global_load_lds(
        (const __attribute__((address_space(1))) unsigned int*)g,
        (__attribute__((address_space(3))) unsigned int*)l, 16, 0, 0);
}

__device__ __forceinline__ void split2(float v, _Float16& h, _Float16& l)
{
    _Float16 hh = (_Float16)v;
    h = hh;
    l = (_Float16)((v - (float)hh) * LOSCALE);
}

// ------------------------------------------------------------------
// fp16-split MFMA GEMM: C[b][m][n] = sum_k A[m][k]*Bt[n][k]  (A.Bt)
// Planes K-chunk-swizzled. Tile 128x128, BK=32, 4 waves x (64x64).
// EPI=0 plain store; EPI=1 pair epilogue -((xx[m]-2v)+xx[n]).
// Plain __launch_bounds__(256): (256,4) forced VGPR=64 -> acc spill (R5).
// ------------------------------------------------------------------
template <int EPI>
__launch_bounds__(256) __global__
void hgemm_k(const _Float16* __restrict__ Ahi, const _Float16* __restrict__ Alo,
             long long sAb, int lda,
             const _Float16* __restrict__ Bhi, const _Float16* __restrict__ Blo,
             long long sBb, int ldb,
             float* __restrict__ C, long long sCb, int ldc,
             int Mreal, int Kk, const float* __restrict__ xx)
{
    __shared__ _Float16 sm[16384];   // Ahi[0,4096) Alo[4096) Bhi[8192) Blo[12288)
    const int b = blockIdx.z;
    const int m0 = blockIdx.y * 128, n0 = blockIdx.x * 128;
    const int tid = threadIdx.x;
    const int w = tid >> 6, lane = tid & 63;
    const int quad = lane >> 4, r16 = lane & 15;
    const int wm = (w >> 1) * 64, wn = (w & 1) * 64;
    const int sq = (r16 >> 1) & 3;

    const _Float16* Ah = Ahi + (long long)b * sAb;
    const _Float16* Al = Alo + (long long)b * sAb;
    const _Float16* Bh = Bhi + (long long)b * sBb;
    const _Float16* Bl = Blo + (long long)b * sBb;

    floatx4 acc_h[4][4], acc_m[4][4];
#pragma unroll
    for (int i = 0; i < 4; i++)
#pragma unroll
        for (int j = 0; j < 4; j++) {
            acc_h[i][j] = (floatx4){0.f, 0.f, 0.f, 0.f};
            acc_m[i][j] = (floatx4){0.f, 0.f, 0.f, 0.f};
        }

    const int kchunk = ((quad + sq) & 3) * 8;

    for (int k0 = 0; k0 < Kk; k0 += 32) {
#pragma unroll
        for (int q = 0; q < 2; q++) {
            int idx = q * 256 + tid;
            int row = idx >> 2;
            int seg = (idx & 3) * 8;
            long long aoff = (long long)(m0 + row) * lda + k0 + seg;
            long long boff = (long long)(n0 + row) * ldb + k0 + seg;
            glds16(Ah + aoff, &sm[idx * 8]);
            glds16(Al + aoff, &sm[4096 + idx * 8]);
            glds16(Bh + boff, &sm[8192 + idx * 8]);
            glds16(Bl + boff, &sm[12288 + idx * 8]);
        }
        __syncthreads();

        half8 ah[4], al[4];
#pragma unroll
        for (int i = 0; i < 4; i++) {
            int off = (wm + i * 16 + r16) * 32 + kchunk;
            ah[i] = *(const half8*)&sm[off];
            al[i] = *(const half8*)&sm[4096 + off];
        }
#pragma unroll
        for (int j = 0; j < 4; j++) {
            int off = (wn + j * 16 + r16) * 32 + kchunk;
            half8 bh = *(const half8*)&sm[8192 + off];
            half8 bl = *(const half8*)&sm[12288 + off];
#pragma unroll
            for (int i = 0; i < 4; i++) {
                acc_h[i][j] = __builtin_amdgcn_mfma_f32_16x16x32_f16(ah[i], bh, acc_h[i][j], 0, 0, 0);
                acc_m[i][j] = __builtin_amdgcn_mfma_f32_16x16x32_f16(ah[i], bl, acc_m[i][j], 0, 0, 0);
                acc_m[i][j] = __builtin_amdgcn_mfma_f32_16x16x32_f16(al[i], bh, acc_m[i][j], 0, 0, 0);
            }
        }
        __syncthreads();
    }

    float* Cb = C + (long long)b * sCb;
    const float* xxp = EPI ? (xx + (long long)b * Nsz) : xx;
#pragma unroll
    for (int i = 0; i < 4; i++) {
#pragma unroll
        for (int r = 0; r < 4; r++) {
            int gm = m0 + wm + i * 16 + quad * 4 + r;
            if (gm >= Mreal) continue;
            float xm = EPI ? xxp[gm] : 0.f;
#pragma unroll
            for (int j = 0; j < 4; j++) {
                int gn = n0 + wn + j * 16 + r16;
                float v = acc_h[i][j][r] + acc_m[i][j][r] * INV_LOSCALE;
                if (EPI == 1) v = -((xm - 2.f * v) + xxp[gn]);
                Cb[(long long)gm * ldc + gn] = v;
            }
        }
    }
}

// ------------------------------------------------------------------
// Exact top-8 per row via threshold method. One wave per row.
// pass1: per-lane sorted-8 of ordered-u32 VALUES (min/max network),
//        butterfly bitonic merge across 64 lanes -> T = 8th largest.
// pass2: ballot-emit indices {v>T} (<=7 of them) then lowest-index {v==T}
//        to fill 8. Exactly jax.lax.top_k's set semantics.
// ------------------------------------------------------------------
__launch_bounds__(256) __global__
void topk8_thresh_k(const float* __restrict__ pair, int* __restrict__ idxo)
{
    const int lane = threadIdx.x & 63;
    const int row = blockIdx.x * 4 + (threadIdx.x >> 6);
    const float* pr = pair + (size_t)row * Nsz;

    unsigned vals[32];
#pragma unroll
    for (int c = 0; c < 32; c++) {
        unsigned u = __float_as_uint(pr[c * 64 + lane]);
        vals[c] = (u & 0x80000000u) ? ~u : (u | 0x80000000u);
    }

    // per-lane sorted-8 (descending, multiset)
    unsigned t[8] = {0, 0, 0, 0, 0, 0, 0, 0};
#pragma unroll
    for (int c = 0; c < 32; c++) {
        unsigned key = vals[c];
#pragma unroll
        for (int j = 7; j >= 1; --j) {
            unsigned m = t[j - 1] < key ? t[j - 1] : key;
            t[j] = t[j] > m ? t[j] : m;
        }
        t[0] = t[0] > key ? t[0] : key;
    }
    // butterfly merge across 64 lanes: top-8 of two sorted-8 lists is
    // max(A[i], B[7-i]) (bitonic), then 3-stage clean to descending.
#pragma unroll
    for (int d = 1; d < 64; d <<= 1) {
        unsigned oth[8];
#pragma unroll
        for (int j = 0; j < 8; j++) oth[j] = __shfl_xor(t[j], d, 64);
        unsigned c2[8];
#pragma unroll
        for (int j = 0; j < 8; j++) {
            unsigned a = t[j], b2 = oth[7 - j];
            c2[j] = a > b2 ? a : b2;
        }
#define CE(A, B) { unsigned x = c2[A], y = c2[B]; c2[A] = x > y ? x : y; c2[B] = x > y ? y : x; }
        CE(0, 4) CE(1, 5) CE(2, 6) CE(3, 7)
        CE(0, 2) CE(1, 3) CE(4, 6) CE(5, 7)
        CE(0, 1) CE(2, 3) CE(4, 5) CE(6, 7)
#undef CE
#pragma unroll
        for (int j = 0; j < 8; j++) t[j] = c2[j];
    }
    const unsigned T = t[7];

    const unsigned long long lmask = (1ull << lane) - 1ull;
    int* op = idxo + (size_t)row * 8;
    int g = 0;
#pragma unroll
    for (int c = 0; c < 32; c++) {
        unsigned long long m = __ballot(vals[c] > T);
        if (vals[c] > T) op[g + __popcll(m & lmask)] = c * 64 + lane;
        g += __popcll(m);
    }
    const int needed = 8 - g;
    int e = 0;
    for (int c = 0; c < 32; c++) {
        if (e >= needed) break;
        unsigned long long m = __ballot(vals[c] == T);
        int pos = e + __popcll(m & lmask);
        if (vals[c] == T && pos < needed) op[g + pos] = c * 64 + lane;
        e += __popcll(m);
    }
}

// ------------------------------------------------------------------
// fp32 SGEMM (layer-1 only, K=3)
// ------------------------------------------------------------------
__launch_bounds__(256) __global__
void sgemm_k(const float* __restrict__ A, int lda,
             const float* __restrict__ Bm, long long sBb, int ldb,
             float* __restrict__ C, long long sCb, int ldc,
             int M, int Kk)
{
    __shared__ float As[16][64];
    __shared__ float Bs[16][64];
    const int b = blockIdx.z;
    const float* Bb = Bm + (long long)b * sBb;
    const int m0 = blockIdx.y * 64, n0 = blockIdx.x * 64;
    const int tid = threadIdx.x;
    const int am = tid >> 2, ak = (tid & 3) * 4;
    const int bk = tid >> 6, bn = tid & 63;
    const int tx = tid & 15, ty = tid >> 4;
    float acc[4][4] = {};
    for (int k0 = 0; k0 < Kk; k0 += 16) {
#pragma unroll
        for (int i = 0; i < 4; i++) {
            int gk = k0 + ak + i;
            int gm = m0 + am;
            As[ak + i][am] = (gk < Kk && gm < M) ? A[(long long)gm * lda + gk] : 0.f;
        }
#pragma unroll
        for (int i = 0; i < 4; i++) {
            int kk = bk + i * 4;
            int gk = k0 + kk;
            Bs[kk][bn] = (gk < Kk) ? Bb[(long long)gk * ldb + (n0 + bn)] : 0.f;
        }
        __syncthreads();
#pragma unroll
        for (int kk = 0; kk < 16; kk++) {
            float a[4], bb2[4];
#pragma unroll
            for (int i = 0; i < 4; i++) a[i] = As[kk][ty * 4 + i];
#pragma unroll
            for (int j = 0; j < 4; j++) bb2[j] = Bs[kk][tx * 4 + j];
#pragma unroll
            for (int i = 0; i < 4; i++)
#pragma unroll
                for (int j = 0; j < 4; j++)
                    acc[i][j] = fmaf(a[i], bb2[j], acc[i][j]);
        }
        __syncthreads();
    }
    float* Cb = C + (long long)b * sCb;
#pragma unroll
    for (int i = 0; i < 4; i++) {
        int gm = m0 + ty * 4 + i;
        if (gm >= M) continue;
#pragma unroll
        for (int j = 0; j < 4; j++)
            Cb[(long long)gm * ldc + n0 + tx * 4 + j] = acc[i][j];
    }
}

// ------------------------------------------------------------------
// One-shot prep: xt transpose + layer-1 fp32 wcat + weight plane splits.
// ------------------------------------------------------------------
#define T0 16384
#define T1 (T0 + 192)
#define T2 (T1 + 16384)
#define T3 (T2 + 65536)
#define T4 (T3 + 262144)
#define T5 (T4 + 983040)
#define T6 (T5 + 524288)
#define T7 (T6 + 65536)
#define WOFF_E1 0
#define WOFF_E2 16384
#define WOFF_E3 81920
#define WOFF_W4 344064
#define WOFF_M1 1327104
#define WOFF_M2 1851392

__device__ __forceinline__ void split_plain(const float* W, _Float16* wh, _Float16* wl,
                                            size_t base, int t, int M, int Kk)
{
    int oo = t / Kk, c = t - oo * Kk;
    float v = (oo < M) ? W[(size_t)oo * Kk + c] : 0.f;
    _Float16 h, l;
    split2(v, h, l);
    size_t d = base + (size_t)oo * Kk + swzk(c, oo);
    wh[d] = h; wl[d] = l;
}

__device__ __forceinline__ void split_edge(const float* W, _Float16* wh, _Float16* wl,
                                           size_t base, int t, int O, int C)
{
    int oo = t / C, c = t - oo * C;
    float v;
    if (oo < O) v = W[(size_t)oo * 2 * C + c];
    else { int o2 = oo - O; v = W[(size_t)o2 * 2 * C + C + c] - W[(size_t)o2 * 2 * C + c]; }
    _Float16 h, l;
    split2(v, h, l);
    size_t d = base + (size_t)oo * C + swzk(c, oo);
    wh[d] = h; wl[d] = l;
}

__global__ void mega_prep_k(const float* __restrict__ x,
                            const float* __restrict__ W0, const float* __restrict__ W1,
                            const float* __restrict__ W2, const float* __restrict__ W3,
                            const float* __restrict__ W4, const float* __restrict__ Wm1,
                            const float* __restrict__ Wm2,
                            float* __restrict__ xt, float* __restrict__ wcat32,
                            _Float16* __restrict__ wh, _Float16* __restrict__ wl)
{
    int t = blockIdx.x * 256 + threadIdx.x;
    if (t < T0) {
        int n = t & (Nsz - 1), b = t >> 11;
#pragma unroll
        for (int c = 0; c < 3; c++)
            xt[((size_t)b * 3 + c) * Nsz + n] = x[((size_t)b * Nsz + n) * 3 + c];
    } else if (t < T1) {
        int u = t - T0;
        int oo = u / 3, c = u % 3;
        float a = W0[(size_t)oo * 6 + c];
        float b2 = W0[(size_t)oo * 6 + 3 + c];
        wcat32[(size_t)oo * 3 + c] = a;
        wcat32[(size_t)(64 + oo) * 3 + c] = b2 - a;
    } else if (t < T2) {
        split_edge(W1, wh, wl, WOFF_E1, t - T1, 128, 64);
    } else if (t < T3) {
        split_edge(W2, wh, wl, WOFF_E2, t - T2, 256, 128);
    } else if (t < T4) {
        split_edge(W3, wh, wl, WOFF_E3, t - T3, 512, 256);
    } else if (t < T5) {
        split_plain(W4, wh, wl, WOFF_W4, t - T4, 1024, 960);
    } else if (t < T6) {
        split_plain(Wm1, wh, wl, WOFF_M1, t - T5, 512, 1024);
    } else if (t < T7) {
        split_plain(Wm2, wh, wl, WOFF_M2, t - T6, 70, 512);
    }
}

// xx[b,n] = sum_c v^2 from planes, dropping lo^2 (matches GEMM's form).
__global__ void xx_planes_k(const _Float16* __restrict__ catA, const _Float16* __restrict__ catB,
                            float* __restrict__ xx, int off, int C)
{
    int t = blockIdx.x * 256 + threadIdx.x;
    if (t >= Bsz * Nsz) return;
    int n = t & (Nsz - 1), b = t >> 11;
    size_t base = ((size_t)b * Nsz + n) * 1024 + off;
    float s = 0.f;
    for (int c8 = 0; c8 < C / 8; c8++) {
        half8 h = *(const half8*)&catA[base + c8 * 8];
        half8 l = *(const half8*)&catB[base + c8 * 8];
#pragma unroll
        for (int e = 0; e < 8; e++) {
            float vh = (float)h[e];
            float vl = (float)l[e] * INV_LOSCALE;
            s = fmaf(vh, vh, s);
            s = fmaf(2.f * vh, vl, s);
        }
    }
    xx[t] = s;
}

// gather + max-pool + stats + transpose + split (swizzled write)
__global__ void gather_pool_t_k(const float* __restrict__ R, const int* __restrict__ idx,
                                _Float16* __restrict__ catA, _Float16* __restrict__ catB,
                                float* __restrict__ part, int O, int off)
{
    __shared__ float tile[64][65];
    const int tid = threadIdx.x;
    const int lane = tid & 63, w = tid >> 6;
    const int n0 = blockIdx.x * 64, o0 = blockIdx.y * 64, b = blockIdx.z;
    const int n = n0 + lane;

    int id[8];
    {
        const int* ip = idx + ((size_t)b * Nsz + n) * 8;
#pragma unroll
        for (int k = 0; k < 8; k++) id[k] = ip[k];
    }
    const float* Rb = R + (size_t)b * 2 * O * Nsz;
#pragma unroll
    for (int i = 0; i < 16; i++) {
        int o_l = w + i * 4;
        int o = o0 + o_l;
        const float* P = Rb + (size_t)o * Nsz;
        float q = Rb[(size_t)(O + o) * Nsz + n];
        float hmax = -INFINITY, s1 = 0.f, s2 = 0.f;
#pragma unroll
        for (int k = 0; k < 8; k++) {
            float h = P[id[k]] + q;
            hmax = fmaxf(hmax, h);
            s1 += h;
            s2 += h * h;
        }
        tile[o_l][lane] = hmax;
#pragma unroll
        for (int offs = 32; offs; offs >>= 1) {
            s1 += __shfl_xor(s1, offs, 64);
            s2 += __shfl_xor(s2, offs, 64);
        }
        if (lane == 0) {
            size_t pi = ((size_t)o * Bsz + b) * 32 + blockIdx.x;
            part[pi * 2] = s1;
            part[pi * 2 + 1] = s2;
        }
    }
    __syncthreads();
    int n_l = tid >> 2, quad = tid & 3;
    int nrow = n0 + n_l;
    half8 h0, h1, l0, l1;
#pragma unroll
    for (int e = 0; e < 8; e++) {
        _Float16 hh, ll;
        split2(tile[quad * 16 + e][n_l], hh, ll);
        h0[e] = hh; l0[e] = ll;
        split2(tile[quad * 16 + 8 + e][n_l], hh, ll);
        h1[e] = hh; l1[e] = ll;
    }
    size_t rowb = ((size_t)b * Nsz + nrow) * 1024;
    int c0 = off + o0 + quad * 16;
    *(half8*)&catA[rowb + swzk(c0, nrow)] = h0;
    *(half8*)&catA[rowb + swzk(c0 + 8, nrow)] = h1;
    *(half8*)&catB[rowb + swzk(c0, nrow)] = l0;
    *(half8*)&catB[rowb + swzk(c0 + 8, nrow)] = l1;
}

__global__ void stats_reduce_k(const float* __restrict__ part, float* __restrict__ stats)
{
    int o2 = blockIdx.x;
    int t = threadIdx.x;
    float s1 = part[((size_t)o2 * 256 + t) * 2];
    float s2 = part[((size_t)o2 * 256 + t) * 2 + 1];
#pragma unroll
    for (int off = 32; off; off >>= 1) { s1 += __shfl_xor(s1, off, 64); s2 += __shfl_xor(s2, off, 64); }
    __shared__ float sh[8];
    int w = t >> 6;
    if ((t & 63) == 0) { sh[w] = s1; sh[4 + w] = s2; }
    __syncthreads();
    if (t == 0) {
        stats[2 * o2] = sh[0] + sh[1] + sh[2] + sh[3];
        stats[2 * o2 + 1] = sh[4] + sh[5] + sh[6] + sh[7];
    }
}

__global__ void fc_stats_k(const float* __restrict__ buf, float* __restrict__ stats, int O)
{
    int oo = blockIdx.x;
    int t = threadIdx.x;
    float s1 = 0.f, s2 = 0.f;
    for (int i = t; i < Bsz * Nsz; i += 256) {
        int b = i >> 11, n = i & (Nsz - 1);
        float v = buf[((size_t)b * O + oo) * Nsz + n];
        s1 += v; s2 += v * v;
    }
#pragma unroll
    for (int off = 32; off; off >>= 1) { s1 += __shfl_xor(s1, off, 64); s2 += __shfl_xor(s2, off, 64); }
    __shared__ float sh[8];
    int w = t >> 6;
    if ((t & 63) == 0) { sh[w] = s1; sh[4 + w] = s2; }
    __syncthreads();
    if (t == 0) {
        stats[2 * oo] = sh[0] + sh[1] + sh[2] + sh[3];
        stats[2 * oo + 1] = sh[4] + sh[5] + sh[6] + sh[7];
    }
}

// in-place BN+lrelu on catT plane slice cols [off, off+O); swizzle-aware
__global__ void bn_t_k(_Float16* __restrict__ catA, _Float16* __restrict__ catB,
                       const float* __restrict__ stats, int off, int O, float invCnt)
{
    int per_n = O / 8;
    size_t t = (size_t)blockIdx.x * 256 + threadIdx.x;
    if (t >= (size_t)Bsz * Nsz * per_n) return;
    int c8 = (int)(t % per_n);
    size_t rest = t / per_n;
    int n = (int)(rest & (Nsz - 1));
    int b = (int)(rest >> 11);
    size_t base = ((size_t)b * Nsz + n) * 1024 + off + c8 * 8;
    int oo_base = ((c8 >> 2) << 5) + ((((c8 & 3) - (n >> 1)) & 3) << 3);
    half8 h = *(const half8*)&catA[base];
    half8 l = *(const half8*)&catB[base];
    half8 ho, lo;
#pragma unroll
    for (int e = 0; e < 8; e++) {
        int oo = oo_base + e;
        float mean = stats[2 * oo] * invCnt;
        float var = stats[2 * oo + 1] * invCnt - mean * mean;
        float v = (float)h[e] + (float)l[e] * INV_LOSCALE;
        float z = (v - mean) / sqrtf(var + EPSV);
        z = z >= 0.f ? z : NSLOPE * z;
        _Float16 hh, ll;
        split2(z, hh, ll);
        ho[e] = hh; lo[e] = ll;
    }
    *(half8*)&catA[base] = ho;
    *(half8*)&catB[base] = lo;
}

// fp32 [b][O][n] + BN + lrelu -> swizzled transposed planes
__global__ void bn_split_t_k(const float* __restrict__ src, const float* __restrict__ stats,
                             _Float16* __restrict__ dA, _Float16* __restrict__ dB,
                             int O, int ldt, float invCnt)
{
    __shared__ float tile[64][65];
    const int tid = threadIdx.x;
    const int n0 = blockIdx.x * 64, o0 = blockIdx.y * 64, b = blockIdx.z;
#pragma unroll
    for (int i = 0; i < 16; i++) {
        int flat = tid + 256 * i;
        int o_l = flat >> 6, n_l = flat & 63;
        int oo = o0 + o_l;
        float mean = stats[2 * oo] * invCnt;
        float var = stats[2 * oo + 1] * invCnt - mean * mean;
        float v = src[((size_t)b * O + oo) * Nsz + n0 + n_l];
        float z = (v - mean) / sqrtf(var + EPSV);
        tile[o_l][n_l] = z >= 0.f ? z : NSLOPE * z;
    }
    __syncthreads();
    int n_l = tid >> 2, quad = tid & 3;
    int nrow = n0 + n_l;
    half8 h0, h1, l0, l1;
#pragma unroll
    for (int e = 0; e < 8; e++) {
        _Float16 hh, ll;
        split2(tile[quad * 16 + e][n_l], hh, ll);
        h0[e] = hh; l0[e] = ll;
        split2(tile[quad * 16 + 8 + e][n_l], hh, ll);
        h1[e] = hh; l1[e] = ll;
    }
    size_t rowb = ((size_t)b * Nsz + nrow) * ldt;
    int c0 = o0 + quad * 16;
    *(half8*)&dA[rowb + swzk(c0, nrow)] = h0;
    *(half8*)&dA[rowb + swzk(c0 + 8, nrow)] = h1;
    *(half8*)&dB[rowb + swzk(c0, nrow)] = l0;
    *(half8*)&dB[rowb + swzk(c0 + 8, nrow)] = l1;
}

// argmax_n(logits + gumbel(u)); exact one-hot to out (70,B,N,1)
__global__ void gumbel_onehot_k(const float* __restrict__ logits, const float* __restrict__ u,
                                float* __restrict__ out)
{
    int lane = threadIdx.x & 63;
    int wv = threadIdx.x >> 6;
    int row = blockIdx.x * 4 + wv;      // row = b*70 + o
    int b = row / 70, oo = row % 70;
    const float* L = logits + (size_t)row * Nsz;
    const float* U = u + (size_t)row * Nsz;
    float bv = -INFINITY; int bi = 0x7fffffff;
    for (int n = lane; n < Nsz; n += 64) {
        float g = -logf(-logf(U[n]));
        float z = L[n] + g;
        if (z > bv) { bv = z; bi = n; }
    }
#pragma unroll
    for (int off = 32; off; off >>= 1) {
        float ov = __shfl_xor(bv, off, 64);
        int oi = __shfl_xor(bi, off, 64);
        if (ov > bv || (ov == bv && oi < bi)) { bv = ov; bi = oi; }
    }
    float* Or = out + ((size_t)oo * Bsz + b) * Nsz;
    for (int n = lane; n < Nsz; n += 64) Or[n] = (n == bi) ? 1.f : 0.f;
}

extern "C" void kernel_launch(void* const* d_in, const int* in_sizes, int n_in,
                              void* d_out, int out_size, void* d_ws, size_t ws_size,
                              hipStream_t stream)
{
    (void)in_sizes; (void)n_in; (void)out_size; (void)ws_size;
    const float* x   = (const float*)d_in[0];
    const int*   sn  = (const int*)d_in[1];
    const float* un  = (const float*)d_in[2];
    const float* W0  = (const float*)d_in[3];
    const float* W1  = (const float*)d_in[4];
    const float* W2  = (const float*)d_in[5];
    const float* W3  = (const float*)d_in[6];
    const float* W4  = (const float*)d_in[7];
    const float* Wm1 = (const float*)d_in[8];
    const float* Wm2 = (const float*)d_in[9];
    float* out = (float*)d_out;

    char* ws = (char*)d_ws;
    size_t o = 0;
    _Float16* catA = (_Float16*)(ws + o); o += (size_t)Bsz * Nsz * 1024 * 2;  // 33.5 MB
    _Float16* catB = (_Float16*)(ws + o); o += (size_t)Bsz * Nsz * 1024 * 2;  // 33.5 MB
    float* R       = (float*)(ws + o);    o += (size_t)Bsz * 1024 * Nsz * 4;  // 67 MB
    _Float16* wHi  = (_Float16*)(ws + o); o += (size_t)2 * 1024 * 1024 * 2;   // 4 MB
    _Float16* wLo  = (_Float16*)(ws + o); o += (size_t)2 * 1024 * 1024 * 2;   // 4 MB
    float* xt      = (float*)(ws + o);    o += (size_t)Bsz * 3 * Nsz * 4;
    float* xxb     = (float*)(ws + o);    o += (size_t)Bsz * Nsz * 4;
    float* wcat32  = (float*)(ws + o);    o += 4096;
    float* part    = (float*)(ws + o);    o += (size_t)512 * Bsz * 32 * 2 * 4;
    float* stats   = (float*)(ws + o);    o += 2048 * 4;
    int* idxb      = (int*)(ws + o);      o += (size_t)Bsz * Nsz * Ksz * 4;
    float* logits  = R + (size_t)12 * 1024 * 1024;      // inside R (hm region dead by then)

    const long long catStride = (long long)Nsz * 1024;

    // ---- one-shot prep ----
    mega_prep_k<<<(T7 + 255) / 256, 256, 0, stream>>>(x, W0, W1, W2, W3, W4, Wm1, Wm2,
                                                      xt, wcat32, wHi, wLo);

    // ---- edge layer 1 (C=3, O=64, idx = start_neighs), fp32 path ----
    sgemm_k<<<dim3(32, 2, Bsz), 256, 0, stream>>>(wcat32, 3, xt, 3LL * Nsz, Nsz,
                                                  R, 2LL * 64 * Nsz, Nsz, 128, 3);
    gather_pool_t_k<<<dim3(32, 1, Bsz), 256, 0, stream>>>(R, sn, catA, catB, part, 64, 0);
    stats_reduce_k<<<64, 256, 0, stream>>>(part, stats);
    bn_t_k<<<(int)(((size_t)Bsz * Nsz * 8 + 255) / 256), 256, 0, stream>>>(
        catA, catB, stats, 0, 64, 1.f / 131072.f);

    // ---- edge layers 2..4 ----
    struct LayerDesc { int C; int O; int prevOff; int catOff; size_t woff; };
    LayerDesc L[3] = {
        { 64, 128, 0, 64, WOFF_E1 },
        { 128, 256, 64, 192, WOFF_E2 },
        { 256, 512, 192, 448, WOFF_E3 },
    };
    for (int li = 0; li < 3; li++) {
        int C = L[li].C, O = L[li].O;
        int poff = L[li].prevOff;
        xx_planes_k<<<(Bsz * Nsz + 255) / 256, 256, 0, stream>>>(catA, catB, xxb, poff, C);
        // pair = prev^T prev per batch, 4 batches per chunk into R; then exact top-8
        for (int ch = 0; ch < 2; ch++) {
            const _Float16* pA = catA + poff + (size_t)ch * 4 * catStride;
            const _Float16* pB = catB + poff + (size_t)ch * 4 * catStride;
            hgemm_k<1><<<dim3(16, 16, 4), 256, 0, stream>>>(
                pA, pB, catStride, 1024, pA, pB, catStride, 1024,
                R, (long long)Nsz * Nsz, Nsz, Nsz, C, xxb + (size_t)ch * 4 * Nsz);
            topk8_thresh_k<<<4 * Nsz / 4, 256, 0, stream>>>(R, idxb + (size_t)ch * 4 * Nsz * Ksz);
        }
        hgemm_k<0><<<dim3(16, 2 * O / 128, Bsz), 256, 0, stream>>>(
            wHi + L[li].woff, wLo + L[li].woff, 0, C, catA + poff, catB + poff, catStride, 1024,
            R, 2LL * O * Nsz, Nsz, 2 * O, C, nullptr);
        gather_pool_t_k<<<dim3(32, O / 64, Bsz), 256, 0, stream>>>(
            R, idxb, catA, catB, part, O, L[li].catOff);
        stats_reduce_k<<<O, 256, 0, stream>>>(part, stats);
        bn_t_k<<<(int)(((size_t)Bsz * Nsz * (O / 8) + 255) / 256), 256, 0, stream>>>(
            catA, catB, stats, L[li].catOff, O, 1.f / 131072.f);
    }

    // ---- fc head ----
    hgemm_k<0><<<dim3(16, 8, Bsz), 256, 0, stream>>>(
        wHi + WOFF_W4, wLo + WOFF_W4, 0, 960, catA, catB, catStride, 1024,
        R, 1024LL * Nsz, Nsz, 1024, 960, nullptr);
    fc_stats_k<<<1024, 256, 0, stream>>>(R, stats, 1024);
    bn_split_t_k<<<dim3(32, 16, Bsz), 256, 0, stream>>>(R, stats, catA, catB, 1024, 1024,
                                                        1.f / 16384.f);
    hgemm_k<0><<<dim3(16, 4, Bsz), 256, 0, stream>>>(
        wHi + WOFF_M1, wLo + WOFF_M1, 0, 1024, catA, catB, catStride, 1024,
        R, 512LL * Nsz, Nsz, 512, 1024, nullptr);
    fc_stats_k<<<512, 256, 0, stream>>>(R, stats, 512);
    bn_split_t_k<<<dim3(32, 8, Bsz), 256, 0, stream>>>(R, stats, catA, catB, 512, 512,
                                                       1.f / 16384.f);
    hgemm_k<0><<<dim3(16, 1, Bsz), 256, 0, stream>>>(
        wHi + WOFF_M2, wLo + WOFF_M2, 0, 512, catA, catB, (long long)Nsz * 512, 512,
        logits, 70LL * Nsz, Nsz, 70, 512, nullptr);

    gumbel_onehot_k<<<(Bsz * 70) / 4, 256, 0, stream>>>(logits, un, out);
}

// Round 8
// 920.729 us; speedup vs baseline: 2.7464x; 1.2939x over previous
//
#include <hip/hip_runtime.h>
#include <math.h>

#define Bsz 8
#define Nsz 2048
#define Ksz 8
#define NSLOPE 0.2f
#define EPSV 1e-5f
#define LOSCALE 2048.0f
#define INV_LOSCALE (1.0f / 2048.0f)

typedef _Float16 half8 __attribute__((ext_vector_type(8)));
typedef float floatx4 __attribute__((ext_vector_type(4)));

// K-chunk swizzle: within each aligned 32-half K-window of row r, the 8-half
// chunk at original position p is stored at position (p + (r>>1)) & 3.
__device__ __forceinline__ int swzk(int k, int row)
{
    return (k & ~31) | ((((k >> 3) + (row >> 1)) & 3) << 3) | (k & 7);
}

__device__ __forceinline__ void glds16(const _Float16* g, _Float16* l)
{
    __builtin_amdgcn_global_load_lds(
        (const __attribute__((address_space(1))) unsigned int*)g,
        (__attribute__((address_space(3))) unsigned int*)l, 16, 0, 0);
}

__device__ __forceinline__ void split2(float v, _Float16& h, _Float16& l)
{
    _Float16 hh = (_Float16)v;
    h = hh;
    l = (_Float16)((v - (float)hh) * LOSCALE);
}

// ------------------------------------------------------------------
// fp16-split MFMA GEMM: C[b][m][n] = sum_k A[m][k]*Bt[n][k]  (A.Bt)
// Planes K-chunk-swizzled. Tile 128x128, BK=32.
// 512 threads / 8 waves, wave-tile 32x64 (2x4 frags of 16x16x32_f16):
// dual acc = 64 VGPR/thread -> ~110 regs/wave -> 2 blocks (16 waves)/CU.
// (Round-7 4-wave version: 64x64/wave, 128-reg acc -> 1 block/CU, 11% occ.)
// EPI=0 plain store; EPI=1 pair epilogue -((xx[m]-2v)+xx[n]).
// ------------------------------------------------------------------
template <int EPI>
__launch_bounds__(512) __global__
void hgemm_k(const _Float16* __restrict__ Ahi, const _Float16* __restrict__ Alo,
             long long sAb, int lda,
             const _Float16* __restrict__ Bhi, const _Float16* __restrict__ Blo,
             long long sBb, int ldb,
             float* __restrict__ C, long long sCb, int ldc,
             int Mreal, int Kk, const float* __restrict__ xx)
{
    __shared__ _Float16 sm[16384];   // Ahi[0,4096) Alo[4096) Bhi[8192) Blo[12288)
    const int b = blockIdx.z;
    const int m0 = blockIdx.y * 128, n0 = blockIdx.x * 128;
    const int tid = threadIdx.x;          // 0..511
    const int w = tid >> 6, lane = tid & 63;
    const int quad = lane >> 4, r16 = lane & 15;
    const int wm = (w >> 1) * 32, wn = (w & 1) * 64;
    const int sq = (r16 >> 1) & 3;
    const int kchunk = ((quad + sq) & 3) * 8;

    const _Float16* Ah = Ahi + (long long)b * sAb;
    const _Float16* Al = Alo + (long long)b * sAb;
    const _Float16* Bh = Bhi + (long long)b * sBb;
    const _Float16* Bl = Blo + (long long)b * sBb;

    floatx4 acc_h[2][4], acc_m[2][4];
#pragma unroll
    for (int i = 0; i < 2; i++)
#pragma unroll
        for (int j = 0; j < 4; j++) {
            acc_h[i][j] = (floatx4){0.f, 0.f, 0.f, 0.f};
            acc_m[i][j] = (floatx4){0.f, 0.f, 0.f, 0.f};
        }

    const int srow = tid >> 2;            // 0..127
    const int sseg = (tid & 3) * 8;

    for (int k0 = 0; k0 < Kk; k0 += 32) {
        long long aoff = (long long)(m0 + srow) * lda + k0 + sseg;
        long long boff = (long long)(n0 + srow) * ldb + k0 + sseg;
        glds16(Ah + aoff, &sm[tid * 8]);
        glds16(Al + aoff, &sm[4096 + tid * 8]);
        glds16(Bh + boff, &sm[8192 + tid * 8]);
        glds16(Bl + boff, &sm[12288 + tid * 8]);
        __syncthreads();

        half8 ah[2], al[2];
#pragma unroll
        for (int i = 0; i < 2; i++) {
            int off = (wm + i * 16 + r16) * 32 + kchunk;
            ah[i] = *(const half8*)&sm[off];
            al[i] = *(const half8*)&sm[4096 + off];
        }
#pragma unroll
        for (int j = 0; j < 4; j++) {
            int off = (wn + j * 16 + r16) * 32 + kchunk;
            half8 bh = *(const half8*)&sm[8192 + off];
            half8 bl = *(const half8*)&sm[12288 + off];
#pragma unroll
            for (int i = 0; i < 2; i++) {
                acc_h[i][j] = __builtin_amdgcn_mfma_f32_16x16x32_f16(ah[i], bh, acc_h[i][j], 0, 0, 0);
                acc_m[i][j] = __builtin_amdgcn_mfma_f32_16x16x32_f16(ah[i], bl, acc_m[i][j], 0, 0, 0);
                acc_m[i][j] = __builtin_amdgcn_mfma_f32_16x16x32_f16(al[i], bh, acc_m[i][j], 0, 0, 0);
            }
        }
        __syncthreads();
    }

    float* Cb = C + (long long)b * sCb;
    const float* xxp = EPI ? (xx + (long long)b * Nsz) : xx;
#pragma unroll
    for (int i = 0; i < 2; i++) {
#pragma unroll
        for (int r = 0; r < 4; r++) {
            int gm = m0 + wm + i * 16 + quad * 4 + r;
            if (gm >= Mreal) continue;
            float xm = EPI ? xxp[gm] : 0.f;
#pragma unroll
            for (int j = 0; j < 4; j++) {
                int gn = n0 + wn + j * 16 + r16;
                float v = acc_h[i][j][r] + acc_m[i][j][r] * INV_LOSCALE;
                if (EPI == 1) v = -((xm - 2.f * v) + xxp[gn]);
                Cb[(long long)gm * ldc + gn] = v;
            }
        }
    }
}

// ------------------------------------------------------------------
// Exact top-8 per row via threshold method. One wave per row.
// ------------------------------------------------------------------
__launch_bounds__(256) __global__
void topk8_thresh_k(const float* __restrict__ pair, int* __restrict__ idxo)
{
    const int lane = threadIdx.x & 63;
    const int row = blockIdx.x * 4 + (threadIdx.x >> 6);
    const float* pr = pair + (size_t)row * Nsz;

    unsigned vals[32];
#pragma unroll
    for (int c = 0; c < 32; c++) {
        unsigned u = __float_as_uint(pr[c * 64 + lane]);
        vals[c] = (u & 0x80000000u) ? ~u : (u | 0x80000000u);
    }

    unsigned t[8] = {0, 0, 0, 0, 0, 0, 0, 0};
#pragma unroll
    for (int c = 0; c < 32; c++) {
        unsigned key = vals[c];
#pragma unroll
        for (int j = 7; j >= 1; --j) {
            unsigned m = t[j - 1] < key ? t[j - 1] : key;
            t[j] = t[j] > m ? t[j] : m;
        }
        t[0] = t[0] > key ? t[0] : key;
    }
#pragma unroll
    for (int d = 1; d < 64; d <<= 1) {
        unsigned oth[8];
#pragma unroll
        for (int j = 0; j < 8; j++) oth[j] = __shfl_xor(t[j], d, 64);
        unsigned c2[8];
#pragma unroll
        for (int j = 0; j < 8; j++) {
            unsigned a = t[j], b2 = oth[7 - j];
            c2[j] = a > b2 ? a : b2;
        }
#define CE(A, B) { unsigned x = c2[A], y = c2[B]; c2[A] = x > y ? x : y; c2[B] = x > y ? y : x; }
        CE(0, 4) CE(1, 5) CE(2, 6) CE(3, 7)
        CE(0, 2) CE(1, 3) CE(4, 6) CE(5, 7)
        CE(0, 1) CE(2, 3) CE(4, 5) CE(6, 7)
#undef CE
#pragma unroll
        for (int j = 0; j < 8; j++) t[j] = c2[j];
    }
    const unsigned T = t[7];

    const unsigned long long lmask = (1ull << lane) - 1ull;
    int* op = idxo + (size_t)row * 8;
    int g = 0;
#pragma unroll
    for (int c = 0; c < 32; c++) {
        unsigned long long m = __ballot(vals[c] > T);
        if (vals[c] > T) op[g + __popcll(m & lmask)] = c * 64 + lane;
        g += __popcll(m);
    }
    const int needed = 8 - g;
    int e = 0;
    for (int c = 0; c < 32; c++) {
        if (e >= needed) break;
        unsigned long long m = __ballot(vals[c] == T);
        int pos = e + __popcll(m & lmask);
        if (vals[c] == T && pos < needed) op[g + pos] = c * 64 + lane;
        e += __popcll(m);
    }
}

// ------------------------------------------------------------------
// fp32 SGEMM (layer-1 only, K=3)
// ------------------------------------------------------------------
__launch_bounds__(256) __global__
void sgemm_k(const float* __restrict__ A, int lda,
             const float* __restrict__ Bm, long long sBb, int ldb,
             float* __restrict__ C, long long sCb, int ldc,
             int M, int Kk)
{
    __shared__ float As[16][64];
    __shared__ float Bs[16][64];
    const int b = blockIdx.z;
    const float* Bb = Bm + (long long)b * sBb;
    const int m0 = blockIdx.y * 64, n0 = blockIdx.x * 64;
    const int tid = threadIdx.x;
    const int am = tid >> 2, ak = (tid & 3) * 4;
    const int bk = tid >> 6, bn = tid & 63;
    const int tx = tid & 15, ty = tid >> 4;
    float acc[4][4] = {};
    for (int k0 = 0; k0 < Kk; k0 += 16) {
#pragma unroll
        for (int i = 0; i < 4; i++) {
            int gk = k0 + ak + i;
            int gm = m0 + am;
            As[ak + i][am] = (gk < Kk && gm < M) ? A[(long long)gm * lda + gk] : 0.f;
        }
#pragma unroll
        for (int i = 0; i < 4; i++) {
            int kk = bk + i * 4;
            int gk = k0 + kk;
            Bs[kk][bn] = (gk < Kk) ? Bb[(long long)gk * ldb + (n0 + bn)] : 0.f;
        }
        __syncthreads();
#pragma unroll
        for (int kk = 0; kk < 16; kk++) {
            float a[4], bb2[4];
#pragma unroll
            for (int i = 0; i < 4; i++) a[i] = As[kk][ty * 4 + i];
#pragma unroll
            for (int j = 0; j < 4; j++) bb2[j] = Bs[kk][tx * 4 + j];
#pragma unroll
            for (int i = 0; i < 4; i++)
#pragma unroll
                for (int j = 0; j < 4; j++)
                    acc[i][j] = fmaf(a[i], bb2[j], acc[i][j]);
        }
        __syncthreads();
    }
    float* Cb = C + (long long)b * sCb;
#pragma unroll
    for (int i = 0; i < 4; i++) {
        int gm = m0 + ty * 4 + i;
        if (gm >= M) continue;
#pragma unroll
        for (int j = 0; j < 4; j++)
            Cb[(long long)gm * ldc + n0 + tx * 4 + j] = acc[i][j];
    }
}

// ------------------------------------------------------------------
// One-shot prep: xt transpose + layer-1 fp32 wcat + weight plane splits.
// ------------------------------------------------------------------
#define T0 16384
#define T1 (T0 + 192)
#define T2 (T1 + 16384)
#define T3 (T2 + 65536)
#define T4 (T3 + 262144)
#define T5 (T4 + 983040)
#define T6 (T5 + 524288)
#define T7 (T6 + 65536)
#define WOFF_E1 0
#define WOFF_E2 16384
#define WOFF_E3 81920
#define WOFF_W4 344064
#define WOFF_M1 1327104
#define WOFF_M2 1851392

__device__ __forceinline__ void split_plain(const float* W, _Float16* wh, _Float16* wl,
                                            size_t base, int t, int M, int Kk)
{
    int oo = t / Kk, c = t - oo * Kk;
    float v = (oo < M) ? W[(size_t)oo * Kk + c] : 0.f;
    _Float16 h, l;
    split2(v, h, l);
    size_t d = base + (size_t)oo * Kk + swzk(c, oo);
    wh[d] = h; wl[d] = l;
}

__device__ __forceinline__ void split_edge(const float* W, _Float16* wh, _Float16* wl,
                                           size_t base, int t, int O, int C)
{
    int oo = t / C, c = t - oo * C;
    float v;
    if (oo < O) v = W[(size_t)oo * 2 * C + c];
    else { int o2 = oo - O; v = W[(size_t)o2 * 2 * C + C + c] - W[(size_t)o2 * 2 * C + c]; }
    _Float16 h, l;
    split2(v, h, l);
    size_t d = base + (size_t)oo * C + swzk(c, oo);
    wh[d] = h; wl[d] = l;
}

__global__ void mega_prep_k(const float* __restrict__ x,
                            const float* __restrict__ W0, const float* __restrict__ W1,
                            const float* __restrict__ W2, const float* __restrict__ W3,
                            const float* __restrict__ W4, const float* __restrict__ Wm1,
                            const float* __restrict__ Wm2,
                            float* __restrict__ xt, float* __restrict__ wcat32,
                            _Float16* __restrict__ wh, _Float16* __restrict__ wl)
{
    int t = blockIdx.x * 256 + threadIdx.x;
    if (t < T0) {
        int n = t & (Nsz - 1), b = t >> 11;
#pragma unroll
        for (int c = 0; c < 3; c++)
            xt[((size_t)b * 3 + c) * Nsz + n] = x[((size_t)b * Nsz + n) * 3 + c];
    } else if (t < T1) {
        int u = t - T0;
        int oo = u / 3, c = u % 3;
        float a = W0[(size_t)oo * 6 + c];
        float b2 = W0[(size_t)oo * 6 + 3 + c];
        wcat32[(size_t)oo * 3 + c] = a;
        wcat32[(size_t)(64 + oo) * 3 + c] = b2 - a;
    } else if (t < T2) {
        split_edge(W1, wh, wl, WOFF_E1, t - T1, 128, 64);
    } else if (t < T3) {
        split_edge(W2, wh, wl, WOFF_E2, t - T2, 256, 128);
    } else if (t < T4) {
        split_edge(W3, wh, wl, WOFF_E3, t - T3, 512, 256);
    } else if (t < T5) {
        split_plain(W4, wh, wl, WOFF_W4, t - T4, 1024, 960);
    } else if (t < T6) {
        split_plain(Wm1, wh, wl, WOFF_M1, t - T5, 512, 1024);
    } else if (t < T7) {
        split_plain(Wm2, wh, wl, WOFF_M2, t - T6, 70, 512);
    }
}

// xx[b,n] = sum_c v^2 from planes, dropping lo^2 (matches GEMM's form).
__global__ void xx_planes_k(const _Float16* __restrict__ catA, const _Float16* __restrict__ catB,
                            float* __restrict__ xx, int off, int C)
{
    int t = blockIdx.x * 256 + threadIdx.x;
    if (t >= Bsz * Nsz) return;
    int n = t & (Nsz - 1), b = t >> 11;
    size_t base = ((size_t)b * Nsz + n) * 1024 + off;
    float s = 0.f;
    for (int c8 = 0; c8 < C / 8; c8++) {
        half8 h = *(const half8*)&catA[base + c8 * 8];
        half8 l = *(const half8*)&catB[base + c8 * 8];
#pragma unroll
        for (int e = 0; e < 8; e++) {
            float vh = (float)h[e];
            float vl = (float)l[e] * INV_LOSCALE;
            s = fmaf(vh, vh, s);
            s = fmaf(2.f * vh, vl, s);
        }
    }
    xx[t] = s;
}

// gather + max-pool + stats + transpose + split (swizzled write)
__global__ void gather_pool_t_k(const float* __restrict__ R, const int* __restrict__ idx,
                                _Float16* __restrict__ catA, _Float16* __restrict__ catB,
                                float* __restrict__ part, int O, int off)
{
    __shared__ float tile[64][65];
    const int tid = threadIdx.x;
    const int lane = tid & 63, w = tid >> 6;
    const int n0 = blockIdx.x * 64, o0 = blockIdx.y * 64, b = blockIdx.z;
    const int n = n0 + lane;

    int id[8];
    {
        const int* ip = idx + ((size_t)b * Nsz + n) * 8;
#pragma unroll
        for (int k = 0; k < 8; k++) id[k] = ip[k];
    }
    const float* Rb = R + (size_t)b * 2 * O * Nsz;
#pragma unroll
    for (int i = 0; i < 16; i++) {
        int o_l = w + i * 4;
        int o = o0 + o_l;
        const float* P = Rb + (size_t)o * Nsz;
        float q = Rb[(size_t)(O + o) * Nsz + n];
        float hmax = -INFINITY, s1 = 0.f, s2 = 0.f;
#pragma unroll
        for (int k = 0; k < 8; k++) {
            float h = P[id[k]] + q;
            hmax = fmaxf(hmax, h);
            s1 += h;
            s2 += h * h;
        }
        tile[o_l][lane] = hmax;
#pragma unroll
        for (int offs = 32; offs; offs >>= 1) {
            s1 += __shfl_xor(s1, offs, 64);
            s2 += __shfl_xor(s2, offs, 64);
        }
        if (lane == 0) {
            size_t pi = ((size_t)o * Bsz + b) * 32 + blockIdx.x;
            part[pi * 2] = s1;
            part[pi * 2 + 1] = s2;
        }
    }
    __syncthreads();
    int n_l = tid >> 2, quad = tid & 3;
    int nrow = n0 + n_l;
    half8 h0, h1, l0, l1;
#pragma unroll
    for (int e = 0; e < 8; e++) {
        _Float16 hh, ll;
        split2(tile[quad * 16 + e][n_l], hh, ll);
        h0[e] = hh; l0[e] = ll;
        split2(tile[quad * 16 + 8 + e][n_l], hh, ll);
        h1[e] = hh; l1[e] = ll;
    }
    size_t rowb = ((size_t)b * Nsz + nrow) * 1024;
    int c0 = off + o0 + quad * 16;
    *(half8*)&catA[rowb + swzk(c0, nrow)] = h0;
    *(half8*)&catA[rowb + swzk(c0 + 8, nrow)] = h1;
    *(half8*)&catB[rowb + swzk(c0, nrow)] = l0;
    *(half8*)&catB[rowb + swzk(c0 + 8, nrow)] = l1;
}

__global__ void stats_reduce_k(const float* __restrict__ part, float* __restrict__ stats)
{
    int o2 = blockIdx.x;
    int t = threadIdx.x;
    float s1 = part[((size_t)o2 * 256 + t) * 2];
    float s2 = part[((size_t)o2 * 256 + t) * 2 + 1];
#pragma unroll
    for (int off = 32; off; off >>= 1) { s1 += __shfl_xor(s1, off, 64); s2 += __shfl_xor(s2, off, 64); }
    __shared__ float sh[8];
    int w = t >> 6;
    if ((t & 63) == 0) { sh[w] = s1; sh[4 + w] = s2; }
    __syncthreads();
    if (t == 0) {
        stats[2 * o2] = sh[0] + sh[1] + sh[2] + sh[3];
        stats[2 * o2 + 1] = sh[4] + sh[5] + sh[6] + sh[7];
    }
}

__global__ void fc_stats_k(const float* __restrict__ buf, float* __restrict__ stats, int O)
{
    int oo = blockIdx.x;
    int t = threadIdx.x;
    float s1 = 0.f, s2 = 0.f;
    for (int i = t; i < Bsz * Nsz; i += 256) {
        int b = i >> 11, n = i & (Nsz - 1);
        float v = buf[((size_t)b * O + oo) * Nsz + n];
        s1 += v; s2 += v * v;
    }
#pragma unroll
    for (int off = 32; off; off >>= 1) { s1 += __shfl_xor(s1, off, 64); s2 += __shfl_xor(s2, off, 64); }
    __shared__ float sh[8];
    int w = t >> 6;
    if ((t & 63) == 0) { sh[w] = s1; sh[4 + w] = s2; }
    __syncthreads();
    if (t == 0) {
        stats[2 * oo] = sh[0] + sh[1] + sh[2] + sh[3];
        stats[2 * oo + 1] = sh[4] + sh[5] + sh[6] + sh[7];
    }
}

// in-place BN+lrelu on catT plane slice cols [off, off+O); swizzle-aware
__global__ void bn_t_k(_Float16* __restrict__ catA, _Float16* __restrict__ catB,
                       const float* __restrict__ stats, int off, int O, float invCnt)
{
    int per_n = O / 8;
    size_t t = (size_t)blockIdx.x * 256 + threadIdx.x;
    if (t >= (size_t)Bsz * Nsz * per_n) return;
    int c8 = (int)(t % per_n);
    size_t rest = t / per_n;
    int n = (int)(rest & (Nsz - 1));
    int b = (int)(rest >> 11);
    size_t base = ((size_t)b * Nsz + n) * 1024 + off + c8 * 8;
    int oo_base = ((c8 >> 2) << 5) + ((((c8 & 3) - (n >> 1)) & 3) << 3);
    half8 h = *(const half8*)&catA[base];
    half8 l = *(const half8*)&catB[base];
    half8 ho, lo;
#pragma unroll
    for (int e = 0; e < 8; e++) {
        int oo = oo_base + e;
        float mean = stats[2 * oo] * invCnt;
        float var = stats[2 * oo + 1] * invCnt - mean * mean;
        float v = (float)h[e] + (float)l[e] * INV_LOSCALE;
        float z = (v - mean) / sqrtf(var + EPSV);
        z = z >= 0.f ? z : NSLOPE * z;
        _Float16 hh, ll;
        split2(z, hh, ll);
        ho[e] = hh; lo[e] = ll;
    }
    *(half8*)&catA[base] = ho;
    *(half8*)&catB[base] = lo;
}

// fp32 [b][O][n] + BN + lrelu -> swizzled transposed planes
__global__ void bn_split_t_k(const float* __restrict__ src, const float* __restrict__ stats,
                             _Float16* __restrict__ dA, _Float16* __restrict__ dB,
                             int O, int ldt, float invCnt)
{
    __shared__ float tile[64][65];
    const int tid = threadIdx.x;
    const int n0 = blockIdx.x * 64, o0 = blockIdx.y * 64, b = blockIdx.z;
#pragma unroll
    for (int i = 0; i < 16; i++) {
        int flat = tid + 256 * i;
        int o_l = flat >> 6, n_l = flat & 63;
        int oo = o0 + o_l;
        float mean = stats[2 * oo] * invCnt;
        float var = stats[2 * oo + 1] * invCnt - mean * mean;
        float v = src[((size_t)b * O + oo) * Nsz + n0 + n_l];
        float z = (v - mean) / sqrtf(var + EPSV);
        tile[o_l][n_l] = z >= 0.f ? z : NSLOPE * z;
    }
    __syncthreads();
    int n_l = tid >> 2, quad = tid & 3;
    int nrow = n0 + n_l;
    half8 h0, h1, l0, l1;
#pragma unroll
    for (int e = 0; e < 8; e++) {
        _Float16 hh, ll;
        split2(tile[quad * 16 + e][n_l], hh, ll);
        h0[e] = hh; l0[e] = ll;
        split2(tile[quad * 16 + 8 + e][n_l], hh, ll);
        h1[e] = hh; l1[e] = ll;
    }
    size_t rowb = ((size_t)b * Nsz + nrow) * ldt;
    int c0 = o0 + quad * 16;
    *(half8*)&dA[rowb + swzk(c0, nrow)] = h0;
    *(half8*)&dA[rowb + swzk(c0 + 8, nrow)] = h1;
    *(half8*)&dB[rowb + swzk(c0, nrow)] = l0;
    *(half8*)&dB[rowb + swzk(c0 + 8, nrow)] = l1;
}

// argmax_n(logits + gumbel(u)); exact one-hot to out (70,B,N,1)
__global__ void gumbel_onehot_k(const float* __restrict__ logits, const float* __restrict__ u,
                                float* __restrict__ out)
{
    int lane = threadIdx.x & 63;
    int wv = threadIdx.x >> 6;
    int row = blockIdx.x * 4 + wv;      // row = b*70 + o
    int b = row / 70, oo = row % 70;
    const float* L = logits + (size_t)row * Nsz;
    const float* U = u + (size_t)row * Nsz;
    float bv = -INFINITY; int bi = 0x7fffffff;
    for (int n = lane; n < Nsz; n += 64) {
        float g = -logf(-logf(U[n]));
        float z = L[n] + g;
        if (z > bv) { bv = z; bi = n; }
    }
#pragma unroll
    for (int off = 32; off; off >>= 1) {
        float ov = __shfl_xor(bv, off, 64);
        int oi = __shfl_xor(bi, off, 64);
        if (ov > bv || (ov == bv && oi < bi)) { bv = ov; bi = oi; }
    }
    float* Or = out + ((size_t)oo * Bsz + b) * Nsz;
    for (int n = lane; n < Nsz; n += 64) Or[n] = (n == bi) ? 1.f : 0.f;
}

extern "C" void kernel_launch(void* const* d_in, const int* in_sizes, int n_in,
                              void* d_out, int out_size, void* d_ws, size_t ws_size,
                              hipStream_t stream)
{
    (void)in_sizes; (void)n_in; (void)out_size; (void)ws_size;
    const float* x   = (const float*)d_in[0];
    const int*   sn  = (const int*)d_in[1];
    const float* un  = (const float*)d_in[2];
    const float* W0  = (const float*)d_in[3];
    const float* W1  = (const float*)d_in[4];
    const float* W2  = (const float*)d_in[5];
    const float* W3  = (const float*)d_in[6];
    const float* W4  = (const float*)d_in[7];
    const float* Wm1 = (const float*)d_in[8];
    const float* Wm2 = (const float*)d_in[9];
    float* out = (float*)d_out;

    char* ws = (char*)d_ws;
    size_t o = 0;
    _Float16* catA = (_Float16*)(ws + o); o += (size_t)Bsz * Nsz * 1024 * 2;  // 33.5 MB
    _Float16* catB = (_Float16*)(ws + o); o += (size_t)Bsz * Nsz * 1024 * 2;  // 33.5 MB
    float* R       = (float*)(ws + o);    o += (size_t)Bsz * 1024 * Nsz * 4;  // 67 MB
    _Float16* wHi  = (_Float16*)(ws + o); o += (size_t)2 * 1024 * 1024 * 2;   // 4 MB
    _Float16* wLo  = (_Float16*)(ws + o); o += (size_t)2 * 1024 * 1024 * 2;   // 4 MB
    float* xt      = (float*)(ws + o);    o += (size_t)Bsz * 3 * Nsz * 4;
    float* xxb     = (float*)(ws + o);    o += (size_t)Bsz * Nsz * 4;
    float* wcat32  = (float*)(ws + o);    o += 4096;
    float* part    = (float*)(ws + o);    o += (size_t)512 * Bsz * 32 * 2 * 4;
    float* stats   = (float*)(ws + o);    o += 2048 * 4;
    int* idxb      = (int*)(ws + o);      o += (size_t)Bsz * Nsz * Ksz * 4;
    float* logits  = R + (size_t)12 * 1024 * 1024;      // inside R (hm region dead by then)

    const long long catStride = (long long)Nsz * 1024;

    // ---- one-shot prep ----
    mega_prep_k<<<(T7 + 255) / 256, 256, 0, stream>>>(x, W0, W1, W2, W3, W4, Wm1, Wm2,
                                                      xt, wcat32, wHi, wLo);

    // ---- edge layer 1 (C=3, O=64, idx = start_neighs), fp32 path ----
    sgemm_k<<<dim3(32, 2, Bsz), 256, 0, stream>>>(wcat32, 3, xt, 3LL * Nsz, Nsz,
                                                  R, 2LL * 64 * Nsz, Nsz, 128, 3);
    gather_pool_t_k<<<dim3(32, 1, Bsz), 256, 0, stream>>>(R, sn, catA, catB, part, 64, 0);
    stats_reduce_k<<<64, 256, 0, stream>>>(part, stats);
    bn_t_k<<<(int)(((size_t)Bsz * Nsz * 8 + 255) / 256), 256, 0, stream>>>(
        catA, catB, stats, 0, 64, 1.f / 131072.f);

    // ---- edge layers 2..4 ----
    struct LayerDesc { int C; int O; int prevOff; int catOff; size_t woff; };
    LayerDesc L[3] = {
        { 64, 128, 0, 64, WOFF_E1 },
        { 128, 256, 64, 192, WOFF_E2 },
        { 256, 512, 192, 448, WOFF_E3 },
    };
    for (int li = 0; li < 3; li++) {
        int C = L[li].C, O = L[li].O;
        int poff = L[li].prevOff;
        xx_planes_k<<<(Bsz * Nsz + 255) / 256, 256, 0, stream>>>(catA, catB, xxb, poff, C);
        // pair = prev^T prev per batch, 4 batches per chunk into R; then exact top-8
        for (int ch = 0; ch < 2; ch++) {
            const _Float16* pA = catA + poff + (size_t)ch * 4 * catStride;
            const _Float16* pB = catB + poff + (size_t)ch * 4 * catStride;
            hgemm_k<1><<<dim3(16, 16, 4), 512, 0, stream>>>(
                pA, pB, catStride, 1024, pA, pB, catStride, 1024,
                R, (long long)Nsz * Nsz, Nsz, Nsz, C, xxb + (size_t)ch * 4 * Nsz);
            topk8_thresh_k<<<4 * Nsz / 4, 256, 0, stream>>>(R, idxb + (size_t)ch * 4 * Nsz * Ksz);
        }
        hgemm_k<0><<<dim3(16, 2 * O / 128, Bsz), 512, 0, stream>>>(
            wHi + L[li].woff, wLo + L[li].woff, 0, C, catA + poff, catB + poff, catStride, 1024,
            R, 2LL * O * Nsz, Nsz, 2 * O, C, nullptr);
        gather_pool_t_k<<<dim3(32, O / 64, Bsz), 256, 0, stream>>>(
            R, idxb, catA, catB, part, O, L[li].catOff);
        stats_reduce_k<<<O, 256, 0, stream>>>(part, stats);
        bn_t_k<<<(int)(((size_t)Bsz * Nsz * (O / 8) + 255) / 256), 256, 0, stream>>>(
            catA, catB, stats, L[li].catOff, O, 1.f / 131072.f);
    }

    // ---- fc head ----
    hgemm_k<0><<<dim3(16, 8, Bsz), 512, 0, stream>>>(
        wHi + WOFF_W4, wLo + WOFF_W4, 0, 960, catA, catB, catStride, 1024,
        R, 1024LL * Nsz, Nsz, 1024, 960, nullptr);
    fc_stats_k<<<1024, 256, 0, stream>>>(R, stats, 1024);
    bn_split_t_k<<<dim3(32, 16, Bsz), 256, 0, stream>>>(R, stats, catA, catB, 1024, 1024,
                                                        1.f / 16384.f);
    hgemm_k<0><<<dim3(16, 4, Bsz), 512, 0, stream>>>(
        wHi + WOFF_M1, wLo + WOFF_M1, 0, 1024, catA, catB, catStride, 1024,
        R, 512LL * Nsz, Nsz, 512, 1024, nullptr);
    fc_stats_k<<<512, 256, 0, stream>>>(R, stats, 512);
    bn_split_t_k<<<dim3(32, 8, Bsz), 256, 0, stream>>>(R, stats, catA, catB, 512, 512,
                                                       1.f / 16384.f);
    hgemm_k<0><<<dim3(16, 1, Bsz), 512, 0, stream>>>(
        wHi + WOFF_M2, wLo + WOFF_M2, 0, 512, catA, catB, (long long)Nsz * 512, 512,
        logits, 70LL * Nsz, Nsz, 70, 512, nullptr);

    gumbel_onehot_k<<<(Bsz * 70) / 4, 256, 0, stream>>>(logits, un, out);
}